// Round 3
// baseline (730.154 us; speedup 1.0000x reference)
//
#include <hip/hip_runtime.h>

#define RFL(v) __builtin_amdgcn_readfirstlane(v)

constexpr int D = 64;
constexpr int MSG_K = 64;   // edges per wave; relation segments padded to MSG_K
constexpr int SL_K = 8;     // nodes per wave in selfloop kernel

// ---- edge counting: cnt[(dst,rel)] for mean-norm + per-relation histogram ----
__global__ __launch_bounds__(256) void count_kernel(
    const int* __restrict__ dst, const int* __restrict__ et,
    int* __restrict__ cnt, int* __restrict__ hist, int E, int R) {
  __shared__ int lh[128];
  if ((int)threadIdx.x < R) lh[threadIdx.x] = 0;
  __syncthreads();
  int e = blockIdx.x * blockDim.x + threadIdx.x;
  if (e < E) {
    int r = et[e];
    int d = dst[e];
    atomicAdd(&cnt[(long)d * R + r], 1);
    atomicAdd(&lh[r], 1);
  }
  __syncthreads();
  if ((int)threadIdx.x < R) {
    int c = lh[threadIdx.x];
    if (c) atomicAdd(&hist[threadIdx.x], c);
  }
}

// ---- padded exclusive prefix: cursor[r] = sum roundup(hist[r'], MSG_K) ----
__global__ void prefix_kernel(const int* __restrict__ hist, int* __restrict__ cursor, int R) {
  __shared__ int sc[128];
  int l = threadIdx.x;
  int c = (l < R) ? ((hist[l] + MSG_K - 1) & ~(MSG_K - 1)) : 0;
  sc[l] = c;
  __syncthreads();
  for (int ofs = 1; ofs < 128; ofs <<= 1) {
    int v = (l >= ofs) ? sc[l - ofs] : 0;
    __syncthreads();
    sc[l] += v;
    __syncthreads();
  }
  if (l < R) cursor[l] = sc[l] - c;
}

// ---- counting-sort scatter into padded segments; one int4 record per edge ----
__global__ __launch_bounds__(256) void scatter_kernel(
    const int* __restrict__ src, const int* __restrict__ dst, const int* __restrict__ et,
    const int* __restrict__ cnt, int* __restrict__ cursor,
    int4* __restrict__ eidx, int E, int R) {
  __shared__ int lh[128];
  __shared__ int lbase[128];
  if ((int)threadIdx.x < R) lh[threadIdx.x] = 0;
  __syncthreads();
  int e = blockIdx.x * blockDim.x + threadIdx.x;
  int r = 0, lr = 0, s = 0, d = 0;
  bool valid = (e < E);
  if (valid) {
    r = et[e]; s = src[e]; d = dst[e];
    lr = atomicAdd(&lh[r], 1);
  }
  __syncthreads();
  if ((int)threadIdx.x < R) {
    int c = lh[threadIdx.x];
    if (c) lbase[threadIdx.x] = atomicAdd(&cursor[threadIdx.x], c);
  }
  __syncthreads();
  if (valid) {
    int pos = lbase[r] + lr;
    int c = cnt[(long)d * R + r];
    float norm = 1.0f / (float)(c > 0 ? c : 1);
    eidx[pos] = make_int4(s, d, __float_as_int(norm), r);
  }
}

// ---- W column cache as 16 NAMED float4 regs (no alloca -> cannot spill silently) ----
#define REP16(M) M(0) M(1) M(2) M(3) M(4) M(5) M(6) M(7) \
                 M(8) M(9) M(10) M(11) M(12) M(13) M(14) M(15)
#define W_DECL(i) float4 wq##i;
#define W_LOAD(i) wq##i = make_float4(wp[(4*i+0)*64], wp[(4*i+1)*64], \
                                      wp[(4*i+2)*64], wp[(4*i+3)*64]);
#define W_FMA(i)  { float4 xv = xr[i]; \
    acc0 = fmaf(xv.x, wq##i.x, acc0); acc1 = fmaf(xv.y, wq##i.y, acc1); \
    acc0 = fmaf(xv.z, wq##i.z, acc0); acc1 = fmaf(xv.w, wq##i.w, acc1); }

// ---- per-edge matvec, one relation per wave, W column in VGPRs ----
__global__ __launch_bounds__(256, 1) void msg_kernel(
    const float* __restrict__ x, const float* __restrict__ W,
    const int4* __restrict__ eidx, float* __restrict__ agg, int nwaves) {
  const int lane = threadIdx.x & 63;
  const int wave = blockIdx.x * 4 + ((int)threadIdx.x >> 6);
  if (wave >= nwaves) return;
  const long base = (long)wave * MSG_K;
  int4 rec = eidx[base + lane];          // coalesced: one record per lane
  const int r = RFL(rec.w);              // wave-uniform relation
  const float* wp = W + (long)r * (D * D) + lane;
  REP16(W_DECL)
  REP16(W_LOAD)                           // 64 coalesced dword loads -> 64 VGPRs
#pragma unroll 2
  for (int j = 0; j < MSG_K; ++j) {
    int s = __builtin_amdgcn_readlane(rec.x, j);
    int d = __builtin_amdgcn_readlane(rec.y, j);
    float nm = __int_as_float(__builtin_amdgcn_readlane(rec.z, j));
    const float4* xr = (const float4*)(x + (long)s * D);  // wave-uniform address
    float acc0 = 0.f, acc1 = 0.f;
    REP16(W_FMA)
    if (nm != 0.0f)                      // wave-uniform: skips pad slots
      atomicAdd(&agg[(long)d * D + lane], (acc0 + acc1) * nm);
  }
}

// ---- out = relu(agg + x @ Wl), Wl column in VGPRs ----
__global__ __launch_bounds__(256, 1) void selfloop_kernel(
    const float* __restrict__ x, const float* __restrict__ Wl,
    const float* __restrict__ agg, float* __restrict__ out, int N) {
  const int lane = threadIdx.x & 63;
  const int wave = blockIdx.x * 4 + ((int)threadIdx.x >> 6);
  long base = (long)wave * SL_K;
  if (base >= N) return;
  long end = base + SL_K;
  if (end > N) end = N;
  const float* wp = Wl + lane;
  REP16(W_DECL)
  REP16(W_LOAD)
  for (long n = base; n < end; ++n) {
    float acc0 = agg[n * D + lane], acc1 = 0.f;
    const float4* xr = (const float4*)(x + n * D);
    REP16(W_FMA)
    out[n * D + lane] = fmaxf(acc0 + acc1, 0.0f);
  }
}

extern "C" void kernel_launch(void* const* d_in, const int* in_sizes, int n_in,
                              void* d_out, int out_size, void* d_ws, size_t ws_size,
                              hipStream_t stream) {
  const float* x   = (const float*)d_in[0];
  const int* src   = (const int*)d_in[1];
  const int* dst   = (const int*)d_in[2];
  const int* et    = (const int*)d_in[3];
  const float* W1  = (const float*)d_in[4];
  const float* Wl1 = (const float*)d_in[5];
  const float* W2  = (const float*)d_in[6];
  const float* Wl2 = (const float*)d_in[7];
  float* out = (float*)d_out;

  const int N = in_sizes[0] / D;
  const int E = in_sizes[1];
  const int R = in_sizes[4] / (D * D);

  const int Ecap = ((E + MSG_K - 1) & ~(MSG_K - 1)) + R * MSG_K;
  const int nwaves = Ecap / MSG_K;

  char* ws = (char*)d_ws;
  size_t off = 0;
  auto alloc = [&](size_t bytes) -> void* {
    void* p = (void*)(ws + off);
    off += (bytes + 255) & ~(size_t)255;
    return p;
  };
  int*   cnt    = (int*)alloc((size_t)N * R * sizeof(int));
  int*   hist   = (int*)alloc((size_t)R * sizeof(int));
  int*   cursor = (int*)alloc((size_t)R * sizeof(int));
  int4*  eidx   = (int4*)alloc((size_t)(Ecap + MSG_K) * sizeof(int4));
  float* agg    = (float*)alloc((size_t)N * D * sizeof(float));
  float* h      = (float*)alloc((size_t)N * D * sizeof(float));
  (void)ws_size; (void)n_in; (void)out_size;

  const int eb = (E + 255) / 256;
  const int msg_blocks = (nwaves + 3) / 4;
  const int sl_waves = (N + SL_K - 1) / SL_K;
  const int sl_blocks = (sl_waves + 3) / 4;

  // ---- shared preprocessing (same edges for both layers) ----
  hipMemsetAsync(cnt, 0, (size_t)N * R * sizeof(int), stream);
  hipMemsetAsync(hist, 0, (size_t)R * sizeof(int), stream);
  hipMemsetAsync(eidx, 0, (size_t)(Ecap + MSG_K) * sizeof(int4), stream);
  count_kernel<<<eb, 256, 0, stream>>>(dst, et, cnt, hist, E, R);
  prefix_kernel<<<1, 128, 0, stream>>>(hist, cursor, R);
  scatter_kernel<<<eb, 256, 0, stream>>>(src, dst, et, cnt, cursor, eidx, E, R);

  // ---- layer 1 ----
  hipMemsetAsync(agg, 0, (size_t)N * D * sizeof(float), stream);
  msg_kernel<<<msg_blocks, 256, 0, stream>>>(x, W1, eidx, agg, nwaves);
  selfloop_kernel<<<sl_blocks, 256, 0, stream>>>(x, Wl1, agg, h, N);

  // ---- layer 2 ----
  hipMemsetAsync(agg, 0, (size_t)N * D * sizeof(float), stream);
  msg_kernel<<<msg_blocks, 256, 0, stream>>>(h, W2, eidx, agg, nwaves);
  selfloop_kernel<<<sl_blocks, 256, 0, stream>>>(h, Wl2, agg, out, N);
}

// Round 4
// 721.835 us; speedup vs baseline: 1.0115x; 1.0115x over previous
//
#include <hip/hip_runtime.h>

typedef __attribute__((ext_vector_type(8))) short bf16x8;
typedef __attribute__((ext_vector_type(4))) float f32x4;

#define RFL(v) __builtin_amdgcn_readfirstlane(v)

constexpr int D = 64;
constexpr int SEG = 64;   // relation-segment padding granule = edges per wave
constexpr int SL_K = 8;   // nodes per wave in selfloop kernel

__device__ inline unsigned short f2bf(float f) {  // RNE fp32->bf16
  unsigned u = __float_as_uint(f);
  u += 0x7fff + ((u >> 16) & 1);
  return (unsigned short)(u >> 16);
}

// ---- edge counting: packed-byte cnt[(dst,rel)] + per-relation histogram ----
// counts per (dst,rel) are ~Poisson(0.25) -> max ~10, uint8 is safe.
__global__ __launch_bounds__(256) void count_kernel(
    const int* __restrict__ dst, const int* __restrict__ et,
    unsigned int* __restrict__ cntp, int* __restrict__ hist, int E, int R) {
  __shared__ int lh[128];
  if ((int)threadIdx.x < R) lh[threadIdx.x] = 0;
  __syncthreads();
  int e = blockIdx.x * blockDim.x + threadIdx.x;
  if (e < E) {
    int r = et[e];
    int d = dst[e];
    int idx = d * R + r;
    atomicAdd(&cntp[idx >> 2], 1u << ((idx & 3) * 8));
    atomicAdd(&lh[r], 1);
  }
  __syncthreads();
  if ((int)threadIdx.x < R) {
    int c = lh[threadIdx.x];
    if (c) atomicAdd(&hist[threadIdx.x], c);
  }
}

// ---- padded exclusive prefix: cursor[r] = sum roundup(hist[r'], SEG) ----
__global__ void prefix_kernel(const int* __restrict__ hist, int* __restrict__ cursor, int R) {
  __shared__ int sc[128];
  int l = threadIdx.x;
  int c = (l < R) ? ((hist[l] + SEG - 1) & ~(SEG - 1)) : 0;
  sc[l] = c;
  __syncthreads();
  for (int ofs = 1; ofs < 128; ofs <<= 1) {
    int v = (l >= ofs) ? sc[l - ofs] : 0;
    __syncthreads();
    sc[l] += v;
    __syncthreads();
  }
  if (l < R) cursor[l] = sc[l] - c;
}

// ---- counting-sort scatter into padded segments; int4 record per edge ----
__global__ __launch_bounds__(256) void scatter_kernel(
    const int* __restrict__ src, const int* __restrict__ dst, const int* __restrict__ et,
    const unsigned int* __restrict__ cntp, int* __restrict__ cursor,
    int4* __restrict__ eidx, int E, int R) {
  __shared__ int lh[128];
  __shared__ int lbase[128];
  if ((int)threadIdx.x < R) lh[threadIdx.x] = 0;
  __syncthreads();
  int e = blockIdx.x * blockDim.x + threadIdx.x;
  int r = 0, lr = 0, s = 0, d = 0;
  bool valid = (e < E);
  if (valid) {
    r = et[e]; s = src[e]; d = dst[e];
    lr = atomicAdd(&lh[r], 1);
  }
  __syncthreads();
  if ((int)threadIdx.x < R) {
    int c = lh[threadIdx.x];
    if (c) lbase[threadIdx.x] = atomicAdd(&cursor[threadIdx.x], c);
  }
  __syncthreads();
  if (valid) {
    int pos = lbase[r] + lr;
    int idx = d * R + r;
    int c = (cntp[idx >> 2] >> ((idx & 3) * 8)) & 255;
    float norm = 1.0f / (float)(c > 0 ? c : 1);
    eidx[pos] = make_int4(s, d, __float_as_int(norm), r);
  }
}

// ---- fp32 -> bf16 convert (node features) ----
__global__ __launch_bounds__(256) void cvt_x_kernel(
    const float* __restrict__ x, unsigned short* __restrict__ xb, int n) {
  int i = blockIdx.x * 256 + threadIdx.x;
  if (i < n) xb[i] = f2bf(x[i]);
}

// ---- W[r][k][n] fp32 -> WT[r][n][k] bf16 (transpose so B-frags are contiguous) ----
__global__ __launch_bounds__(256) void cvt_w_kernel(
    const float* __restrict__ W, unsigned short* __restrict__ WT, int total) {
  int i = blockIdx.x * 256 + threadIdx.x;
  if (i >= total) return;
  int n = i & 63, k = (i >> 6) & 63, r = i >> 12;
  WT[(r << 12) + (n << 6) + k] = f2bf(W[(r << 12) + (k << 6) + n]);
}

// ---- MFMA msg kernel: one relation per wave (padded segments), 64 edges/wave ----
// A[m][k] = xb[src[m]][k] (m=lane&15, k=quad*8+j), B[k][n] = WT[r][n][k]
// (n=lane&15), C/D: col=lane&15, row=quad*4+reg. 8 MFMAs per 16-edge tile.
__global__ __launch_bounds__(256) __attribute__((amdgpu_waves_per_eu(1, 4)))
void msg_kernel(const unsigned short* __restrict__ xb,
                const unsigned short* __restrict__ WT,
                const int4* __restrict__ eidx,
                float* __restrict__ agg, int nwaves) {
  const int lane = (int)threadIdx.x & 63;
  const int l15 = lane & 15;
  const int q = lane >> 4;
  const int wave = blockIdx.x * 4 + ((int)threadIdx.x >> 6);
  if (wave >= nwaves) return;
  const long base = (long)wave * SEG;
  const int r = RFL(eidx[base].w);          // wave-uniform relation (pad rel=0 safe)
  const unsigned short* wb = WT + ((long)r << 12);
  bf16x8 Bf[4][2];                           // 8 B-frags, invariant across tiles
#pragma unroll
  for (int nt = 0; nt < 4; ++nt)
#pragma unroll
    for (int kh = 0; kh < 2; ++kh)
      Bf[nt][kh] = *(const bf16x8*)(wb + (nt * 16 + l15) * 64 + kh * 32 + q * 8);
#pragma unroll
  for (int t = 0; t < 4; ++t) {
    int4 rec = eidx[base + t * 16 + l15];    // lane l15 holds edge l15 of tile
    const unsigned short* xr = xb + ((long)rec.x << 6);
    bf16x8 A0 = *(const bf16x8*)(xr + q * 8);
    bf16x8 A1 = *(const bf16x8*)(xr + 32 + q * 8);
    f32x4 acc0 = (f32x4)0.0f, acc1 = (f32x4)0.0f, acc2 = (f32x4)0.0f, acc3 = (f32x4)0.0f;
    acc0 = __builtin_amdgcn_mfma_f32_16x16x32_bf16(A0, Bf[0][0], acc0, 0, 0, 0);
    acc0 = __builtin_amdgcn_mfma_f32_16x16x32_bf16(A1, Bf[0][1], acc0, 0, 0, 0);
    acc1 = __builtin_amdgcn_mfma_f32_16x16x32_bf16(A0, Bf[1][0], acc1, 0, 0, 0);
    acc1 = __builtin_amdgcn_mfma_f32_16x16x32_bf16(A1, Bf[1][1], acc1, 0, 0, 0);
    acc2 = __builtin_amdgcn_mfma_f32_16x16x32_bf16(A0, Bf[2][0], acc2, 0, 0, 0);
    acc2 = __builtin_amdgcn_mfma_f32_16x16x32_bf16(A1, Bf[2][1], acc2, 0, 0, 0);
    acc3 = __builtin_amdgcn_mfma_f32_16x16x32_bf16(A0, Bf[3][0], acc3, 0, 0, 0);
    acc3 = __builtin_amdgcn_mfma_f32_16x16x32_bf16(A1, Bf[3][1], acc3, 0, 0, 0);
    float nmv = __int_as_float(rec.z);
#pragma unroll
    for (int rg = 0; rg < 4; ++rg) {
      int row = q * 4 + rg;                  // C/D row = edge within tile
      int dd = __shfl(rec.y, row);
      float nm = __shfl(nmv, row);
      if (nm != 0.0f) {                      // pad rows have norm==0
        float* ap = agg + (long)dd * D + l15;
        atomicAdd(ap + 0,  acc0[rg] * nm);
        atomicAdd(ap + 16, acc1[rg] * nm);
        atomicAdd(ap + 32, acc2[rg] * nm);
        atomicAdd(ap + 48, acc3[rg] * nm);
      }
    }
  }
}

// ---- out = relu(agg + x @ Wl) (exact fp32), optionally emit bf16 copy ----
#define REP16(M) M(0) M(1) M(2) M(3) M(4) M(5) M(6) M(7) \
                 M(8) M(9) M(10) M(11) M(12) M(13) M(14) M(15)
#define W_DECL(i) float4 wq##i;
#define W_LOAD(i) wq##i = make_float4(wp[(4*i+0)*64], wp[(4*i+1)*64], \
                                      wp[(4*i+2)*64], wp[(4*i+3)*64]);
#define W_FMA(i)  { float4 xv = xr[i]; \
    acc0 = fmaf(xv.x, wq##i.x, acc0); acc1 = fmaf(xv.y, wq##i.y, acc1); \
    acc0 = fmaf(xv.z, wq##i.z, acc0); acc1 = fmaf(xv.w, wq##i.w, acc1); }

__global__ __launch_bounds__(256) __attribute__((amdgpu_waves_per_eu(1, 4)))
void selfloop_kernel(const float* __restrict__ x, const float* __restrict__ Wl,
                     const float* __restrict__ agg, float* __restrict__ out,
                     unsigned short* __restrict__ hb, int N) {
  const int lane = (int)threadIdx.x & 63;
  const int wave = blockIdx.x * 4 + ((int)threadIdx.x >> 6);
  long base = (long)wave * SL_K;
  if (base >= N) return;
  long end = base + SL_K;
  if (end > N) end = N;
  const float* wp = Wl + lane;
  REP16(W_DECL)
  REP16(W_LOAD)
  for (long n = base; n < end; ++n) {
    float acc0 = agg[n * D + lane], acc1 = 0.f;
    const float4* xr = (const float4*)(x + n * D);
    REP16(W_FMA)
    float v = fmaxf(acc0 + acc1, 0.0f);
    out[n * D + lane] = v;
    if (hb) hb[n * D + lane] = f2bf(v);
  }
}

extern "C" void kernel_launch(void* const* d_in, const int* in_sizes, int n_in,
                              void* d_out, int out_size, void* d_ws, size_t ws_size,
                              hipStream_t stream) {
  const float* x   = (const float*)d_in[0];
  const int* src   = (const int*)d_in[1];
  const int* dst   = (const int*)d_in[2];
  const int* et    = (const int*)d_in[3];
  const float* W1  = (const float*)d_in[4];
  const float* Wl1 = (const float*)d_in[5];
  const float* W2  = (const float*)d_in[6];
  const float* Wl2 = (const float*)d_in[7];
  float* out = (float*)d_out;

  const int N = in_sizes[0] / D;
  const int E = in_sizes[1];
  const int R = in_sizes[4] / (D * D);

  const int Ecap = ((E + SEG - 1) & ~(SEG - 1)) + R * SEG;
  const int nwaves = Ecap / SEG;

  char* ws = (char*)d_ws;
  size_t off = 0;
  auto alloc = [&](size_t bytes) -> void* {
    void* p = (void*)(ws + off);
    off += (bytes + 255) & ~(size_t)255;
    return p;
  };
  unsigned int* cntp = (unsigned int*)alloc((size_t)((N * R + 3) / 4) * sizeof(unsigned int));
  int*   hist   = (int*)alloc((size_t)R * sizeof(int));
  int*   cursor = (int*)alloc((size_t)R * sizeof(int));
  int4*  eidx   = (int4*)alloc((size_t)(Ecap + SEG) * sizeof(int4));
  float* agg    = (float*)alloc((size_t)N * D * sizeof(float));
  float* h      = (float*)alloc((size_t)N * D * sizeof(float));
  unsigned short* xb  = (unsigned short*)alloc((size_t)N * D * sizeof(unsigned short));
  unsigned short* hb  = (unsigned short*)alloc((size_t)N * D * sizeof(unsigned short));
  unsigned short* WT1 = (unsigned short*)alloc((size_t)R * D * D * sizeof(unsigned short));
  unsigned short* WT2 = (unsigned short*)alloc((size_t)R * D * D * sizeof(unsigned short));
  (void)ws_size; (void)n_in; (void)out_size;

  const int eb = (E + 255) / 256;
  const int msg_blocks = (nwaves + 3) / 4;
  const int sl_waves = (N + SL_K - 1) / SL_K;
  const int sl_blocks = (sl_waves + 3) / 4;
  const int wtot = R * D * D;

  // ---- shared preprocessing ----
  hipMemsetAsync(cntp, 0, (size_t)((N * R + 3) / 4) * sizeof(unsigned int), stream);
  hipMemsetAsync(hist, 0, (size_t)R * sizeof(int), stream);
  hipMemsetAsync(eidx, 0, (size_t)(Ecap + SEG) * sizeof(int4), stream);
  count_kernel<<<eb, 256, 0, stream>>>(dst, et, cntp, hist, E, R);
  prefix_kernel<<<1, 128, 0, stream>>>(hist, cursor, R);
  scatter_kernel<<<eb, 256, 0, stream>>>(src, dst, et, cntp, cursor, eidx, E, R);
  cvt_x_kernel<<<(N * D + 255) / 256, 256, 0, stream>>>(x, xb, N * D);
  cvt_w_kernel<<<(wtot + 255) / 256, 256, 0, stream>>>(W1, WT1, wtot);
  cvt_w_kernel<<<(wtot + 255) / 256, 256, 0, stream>>>(W2, WT2, wtot);

  // ---- layer 1 ----
  hipMemsetAsync(agg, 0, (size_t)N * D * sizeof(float), stream);
  msg_kernel<<<msg_blocks, 256, 0, stream>>>(xb, WT1, eidx, agg, nwaves);
  selfloop_kernel<<<sl_blocks, 256, 0, stream>>>(x, Wl1, agg, h, hb, N);

  // ---- layer 2 ----
  hipMemsetAsync(agg, 0, (size_t)N * D * sizeof(float), stream);
  msg_kernel<<<msg_blocks, 256, 0, stream>>>(hb, WT2, eidx, agg, nwaves);
  selfloop_kernel<<<sl_blocks, 256, 0, stream>>>(h, Wl2, agg, out, nullptr, N);
}

// Round 5
// 661.302 us; speedup vs baseline: 1.1041x; 1.0915x over previous
//
#include <hip/hip_runtime.h>

typedef __attribute__((ext_vector_type(8))) short bf16x8;
typedef __attribute__((ext_vector_type(4))) float f32x4;

#define RFL(v) __builtin_amdgcn_readfirstlane(v)

constexpr int D = 64;
constexpr int SEG = 64;   // relation-segment padding granule = edges per wave
constexpr int SL_K = 8;   // nodes per wave in selfloop kernel

__device__ inline unsigned short f2bf(float f) {  // RNE fp32->bf16
  unsigned u = __float_as_uint(f);
  u += 0x7fff + ((u >> 16) & 1);
  return (unsigned short)(u >> 16);
}

// ---- counting: cnt[(dst,rel)] packed bytes, hist[rel], deg[dst] ----
__global__ __launch_bounds__(256) void count_kernel(
    const int* __restrict__ dst, const int* __restrict__ et,
    unsigned int* __restrict__ cntp, int* __restrict__ hist,
    int* __restrict__ deg, int E, int R) {
  __shared__ int lh[128];
  if ((int)threadIdx.x < R) lh[threadIdx.x] = 0;
  __syncthreads();
  int e = blockIdx.x * blockDim.x + threadIdx.x;
  if (e < E) {
    int r = et[e];
    int d = dst[e];
    int idx = d * R + r;
    atomicAdd(&cntp[idx >> 2], 1u << ((idx & 3) * 8));
    atomicAdd(&deg[d], 1);
    atomicAdd(&lh[r], 1);
  }
  __syncthreads();
  if ((int)threadIdx.x < R) {
    int c = lh[threadIdx.x];
    if (c) atomicAdd(&hist[threadIdx.x], c);
  }
}

// ---- padded exclusive prefix over relations: cursor[r] ----
__global__ void prefix_kernel(const int* __restrict__ hist, int* __restrict__ cursor, int R) {
  __shared__ int sc[128];
  int l = threadIdx.x;
  int c = (l < R) ? ((hist[l] + SEG - 1) & ~(SEG - 1)) : 0;
  sc[l] = c;
  __syncthreads();
  for (int ofs = 1; ofs < 128; ofs <<= 1) {
    int v = (l >= ofs) ? sc[l - ofs] : 0;
    __syncthreads();
    sc[l] += v;
    __syncthreads();
  }
  if (l < R) cursor[l] = sc[l] - c;
}

// ---- exclusive scan over deg[0..N) -> dstoff (N+1) and working copy cur2 ----
__global__ __launch_bounds__(1024) void scan_deg_kernel(
    const int* __restrict__ deg, int* __restrict__ dstoff,
    int* __restrict__ cur2, int N) {
  __shared__ int ls[1024];
  const int T = 1024;
  int t = threadIdx.x;
  int K = (N + T - 1) / T;
  int beg = t * K, fin = min(beg + K, N);
  int s = 0;
  for (int i = beg; i < fin; ++i) s += deg[i];
  ls[t] = s;
  __syncthreads();
  for (int ofs = 1; ofs < T; ofs <<= 1) {
    int v = (t >= ofs) ? ls[t - ofs] : 0;
    __syncthreads();
    ls[t] += v;
    __syncthreads();
  }
  int run = (t == 0) ? 0 : ls[t - 1];
  for (int i = beg; i < fin; ++i) { dstoff[i] = run; cur2[i] = run; run += deg[i]; }
  if (t == 0) dstoff[N] = ls[T - 1];
}

// ---- counting-sort scatter: relation-sorted slot + dst-sorted msg row id ----
// eidx[pos] = {src, jdst, bitcast(norm), rel}; pads stay zero (norm==0).
__global__ __launch_bounds__(256) void scatter_kernel(
    const int* __restrict__ src, const int* __restrict__ dst, const int* __restrict__ et,
    const unsigned int* __restrict__ cntp, int* __restrict__ cursor,
    int* __restrict__ cur2, int4* __restrict__ eidx, int E, int R) {
  __shared__ int lh[128];
  __shared__ int lbase[128];
  if ((int)threadIdx.x < R) lh[threadIdx.x] = 0;
  __syncthreads();
  int e = blockIdx.x * blockDim.x + threadIdx.x;
  int r = 0, lr = 0, s = 0, d = 0;
  bool valid = (e < E);
  if (valid) {
    r = et[e]; s = src[e]; d = dst[e];
    lr = atomicAdd(&lh[r], 1);
  }
  __syncthreads();
  if ((int)threadIdx.x < R) {
    int c = lh[threadIdx.x];
    if (c) lbase[threadIdx.x] = atomicAdd(&cursor[threadIdx.x], c);
  }
  __syncthreads();
  if (valid) {
    int pos = lbase[r] + lr;
    int idx = d * R + r;
    int c = (cntp[idx >> 2] >> ((idx & 3) * 8)) & 255;
    float norm = 1.0f / (float)(c > 0 ? c : 1);
    int jd = atomicAdd(&cur2[d], 1);          // dst-sorted msg row
    eidx[pos] = make_int4(s, jd, __float_as_int(norm), r);
  }
}

// ---- fp32 -> bf16 convert (node features) ----
__global__ __launch_bounds__(256) void cvt_x_kernel(
    const float* __restrict__ x, unsigned short* __restrict__ xb, int n) {
  int i = blockIdx.x * 256 + threadIdx.x;
  if (i < n) xb[i] = f2bf(x[i]);
}

// ---- W[r][k][n] fp32 -> WT[r][n][k] bf16 ----
__global__ __launch_bounds__(256) void cvt_w_kernel(
    const float* __restrict__ W, unsigned short* __restrict__ WT, int total) {
  int i = blockIdx.x * 256 + threadIdx.x;
  if (i >= total) return;
  int n = i & 63, k = (i >> 6) & 63, r = i >> 12;
  WT[(r << 12) + (n << 6) + k] = f2bf(W[(r << 12) + (k << 6) + n]);
}

// ---- Phase A: MFMA matvec, stream normalized msgs (packed bf16, no atomics) ----
// msg row layout (32 dwords): dword o<16 = cols (o, o+16); o>=16 = cols (o+16, o+32).
__global__ __launch_bounds__(256) __attribute__((amdgpu_waves_per_eu(1, 4)))
void msg_kernel(const unsigned short* __restrict__ xb,
                const unsigned short* __restrict__ WT,
                const int4* __restrict__ eidx,
                unsigned int* __restrict__ msgp, int nwaves) {
  const int lane = (int)threadIdx.x & 63;
  const int l15 = lane & 15;
  const int q = lane >> 4;
  const int wave = blockIdx.x * 4 + ((int)threadIdx.x >> 6);
  if (wave >= nwaves) return;
  const long base = (long)wave * SEG;
  const int r = RFL(eidx[base].w);          // wave-uniform relation (pads: rel=0)
  const unsigned short* wb = WT + ((long)r << 12);
  bf16x8 Bf[4][2];
#pragma unroll
  for (int nt = 0; nt < 4; ++nt)
#pragma unroll
    for (int kh = 0; kh < 2; ++kh)
      Bf[nt][kh] = *(const bf16x8*)(wb + (nt * 16 + l15) * 64 + kh * 32 + q * 8);
#pragma unroll
  for (int t = 0; t < 4; ++t) {
    int4 rec = eidx[base + t * 16 + l15];
    const unsigned short* xr = xb + ((long)rec.x << 6);
    bf16x8 A0 = *(const bf16x8*)(xr + q * 8);
    bf16x8 A1 = *(const bf16x8*)(xr + 32 + q * 8);
    f32x4 acc0 = (f32x4)0.0f, acc1 = (f32x4)0.0f, acc2 = (f32x4)0.0f, acc3 = (f32x4)0.0f;
    acc0 = __builtin_amdgcn_mfma_f32_16x16x32_bf16(A0, Bf[0][0], acc0, 0, 0, 0);
    acc0 = __builtin_amdgcn_mfma_f32_16x16x32_bf16(A1, Bf[0][1], acc0, 0, 0, 0);
    acc1 = __builtin_amdgcn_mfma_f32_16x16x32_bf16(A0, Bf[1][0], acc1, 0, 0, 0);
    acc1 = __builtin_amdgcn_mfma_f32_16x16x32_bf16(A1, Bf[1][1], acc1, 0, 0, 0);
    acc2 = __builtin_amdgcn_mfma_f32_16x16x32_bf16(A0, Bf[2][0], acc2, 0, 0, 0);
    acc2 = __builtin_amdgcn_mfma_f32_16x16x32_bf16(A1, Bf[2][1], acc2, 0, 0, 0);
    acc3 = __builtin_amdgcn_mfma_f32_16x16x32_bf16(A0, Bf[3][0], acc3, 0, 0, 0);
    acc3 = __builtin_amdgcn_mfma_f32_16x16x32_bf16(A1, Bf[3][1], acc3, 0, 0, 0);
    float nmv = __int_as_float(rec.z);
#pragma unroll
    for (int rg = 0; rg < 4; ++rg) {
      int row = q * 4 + rg;                  // C/D row = edge within tile
      int jd = __shfl(rec.y, row);           // dst-sorted msg row id
      float nm = __shfl(nmv, row);
      if (nm != 0.0f) {                      // pads: norm==0 -> no store
        unsigned p0 = (unsigned)f2bf(acc0[rg] * nm) | ((unsigned)f2bf(acc1[rg] * nm) << 16);
        unsigned p1 = (unsigned)f2bf(acc2[rg] * nm) | ((unsigned)f2bf(acc3[rg] * nm) << 16);
        unsigned int* mp = msgp + (long)jd * 32;
        mp[l15] = p0;
        mp[16 + l15] = p1;
      }
    }
  }
}

// ---- Phase B: wave per dst, contiguous msg rows, no atomics, no memset ----
__global__ __launch_bounds__(256) void agg_kernel(
    const unsigned int* __restrict__ msgp, const int* __restrict__ dstoff,
    float* __restrict__ agg, int N) {
  const int lane = (int)threadIdx.x & 63;
  const int j = lane & 31;
  const int half = lane >> 5;
  const int d = blockIdx.x * 4 + ((int)threadIdx.x >> 6);
  if (d >= N) return;
  const int off = dstoff[d], end = dstoff[d + 1];
  float a0 = 0.f, a1 = 0.f, b0 = 0.f, b1 = 0.f;
  int i = off + half;
  for (; i + 2 < end; i += 4) {
    unsigned u0 = msgp[(long)i * 32 + j];
    unsigned u1 = msgp[(long)(i + 2) * 32 + j];
    a0 += __uint_as_float(u0 << 16);
    a1 += __uint_as_float(u0 & 0xffff0000u);
    b0 += __uint_as_float(u1 << 16);
    b1 += __uint_as_float(u1 & 0xffff0000u);
  }
  if (i < end) {
    unsigned u0 = msgp[(long)i * 32 + j];
    a0 += __uint_as_float(u0 << 16);
    a1 += __uint_as_float(u0 & 0xffff0000u);
  }
  float aLo = a0 + b0, aHi = a1 + b1;
  aLo += __shfl_xor(aLo, 32);
  aHi += __shfl_xor(aHi, 32);
  if (half == 0) {
    int colLo = (j < 16) ? j : j + 16;       // cols {0..15, 32..47}
    agg[(long)d * D + colLo] = aLo;
    agg[(long)d * D + colLo + 16] = aHi;     // cols {16..31, 48..63}
  }
}

// ---- out = relu(agg + x @ Wl) (exact fp32), optionally emit bf16 copy ----
#define REP16(M) M(0) M(1) M(2) M(3) M(4) M(5) M(6) M(7) \
                 M(8) M(9) M(10) M(11) M(12) M(13) M(14) M(15)
#define W_DECL(i) float4 wq##i;
#define W_LOAD(i) wq##i = make_float4(wp[(4*i+0)*64], wp[(4*i+1)*64], \
                                      wp[(4*i+2)*64], wp[(4*i+3)*64]);
#define W_FMA(i)  { float4 xv = xr[i]; \
    acc0 = fmaf(xv.x, wq##i.x, acc0); acc1 = fmaf(xv.y, wq##i.y, acc1); \
    acc0 = fmaf(xv.z, wq##i.z, acc0); acc1 = fmaf(xv.w, wq##i.w, acc1); }

__global__ __launch_bounds__(256) __attribute__((amdgpu_waves_per_eu(1, 4)))
void selfloop_kernel(const float* __restrict__ x, const float* __restrict__ Wl,
                     const float* __restrict__ agg, float* __restrict__ out,
                     unsigned short* __restrict__ hb, int N) {
  const int lane = (int)threadIdx.x & 63;
  const int wave = blockIdx.x * 4 + ((int)threadIdx.x >> 6);
  long base = (long)wave * SL_K;
  if (base >= N) return;
  long end = base + SL_K;
  if (end > N) end = N;
  const float* wp = Wl + lane;
  REP16(W_DECL)
  REP16(W_LOAD)
  for (long n = base; n < end; ++n) {
    float acc0 = agg[n * D + lane], acc1 = 0.f;
    const float4* xr = (const float4*)(x + n * D);
    REP16(W_FMA)
    float v = fmaxf(acc0 + acc1, 0.0f);
    out[n * D + lane] = v;
    if (hb) hb[n * D + lane] = f2bf(v);
  }
}

extern "C" void kernel_launch(void* const* d_in, const int* in_sizes, int n_in,
                              void* d_out, int out_size, void* d_ws, size_t ws_size,
                              hipStream_t stream) {
  const float* x   = (const float*)d_in[0];
  const int* src   = (const int*)d_in[1];
  const int* dst   = (const int*)d_in[2];
  const int* et    = (const int*)d_in[3];
  const float* W1  = (const float*)d_in[4];
  const float* Wl1 = (const float*)d_in[5];
  const float* W2  = (const float*)d_in[6];
  const float* Wl2 = (const float*)d_in[7];
  float* out = (float*)d_out;

  const int N = in_sizes[0] / D;
  const int E = in_sizes[1];
  const int R = in_sizes[4] / (D * D);

  const int Ecap = ((E + SEG - 1) & ~(SEG - 1)) + R * SEG;
  const int nwaves = Ecap / SEG;

  char* ws = (char*)d_ws;
  size_t off = 0;
  auto alloc = [&](size_t bytes) -> void* {
    void* p = (void*)(ws + off);
    off += (bytes + 255) & ~(size_t)255;
    return p;
  };
  unsigned int* cntp = (unsigned int*)alloc((size_t)((N * R + 3) / 4) * sizeof(unsigned int));
  int*   hist   = (int*)alloc((size_t)R * sizeof(int));
  int*   cursor = (int*)alloc((size_t)R * sizeof(int));
  int*   deg    = (int*)alloc((size_t)N * sizeof(int));
  int*   dstoff = (int*)alloc((size_t)(N + 1) * sizeof(int));
  int*   cur2   = (int*)alloc((size_t)N * sizeof(int));
  int4*  eidx   = (int4*)alloc((size_t)(Ecap + SEG) * sizeof(int4));
  unsigned int* msgp = (unsigned int*)alloc((size_t)E * 32 * sizeof(unsigned int));
  float* agg    = (float*)alloc((size_t)N * D * sizeof(float));
  float* h      = (float*)alloc((size_t)N * D * sizeof(float));
  unsigned short* xb  = (unsigned short*)alloc((size_t)N * D * sizeof(unsigned short));
  unsigned short* hb  = (unsigned short*)alloc((size_t)N * D * sizeof(unsigned short));
  unsigned short* WT1 = (unsigned short*)alloc((size_t)R * D * D * sizeof(unsigned short));
  unsigned short* WT2 = (unsigned short*)alloc((size_t)R * D * D * sizeof(unsigned short));
  (void)ws_size; (void)n_in; (void)out_size;

  const int eb = (E + 255) / 256;
  const int msg_blocks = (nwaves + 3) / 4;
  const int agg_blocks = (N + 3) / 4;
  const int sl_waves = (N + SL_K - 1) / SL_K;
  const int sl_blocks = (sl_waves + 3) / 4;
  const int wtot = R * D * D;

  // ---- shared preprocessing ----
  hipMemsetAsync(cntp, 0, (size_t)((N * R + 3) / 4) * sizeof(unsigned int), stream);
  hipMemsetAsync(hist, 0, (size_t)R * sizeof(int), stream);
  hipMemsetAsync(deg, 0, (size_t)N * sizeof(int), stream);
  hipMemsetAsync(eidx, 0, (size_t)(Ecap + SEG) * sizeof(int4), stream);
  count_kernel<<<eb, 256, 0, stream>>>(dst, et, cntp, hist, deg, E, R);
  prefix_kernel<<<1, 128, 0, stream>>>(hist, cursor, R);
  scan_deg_kernel<<<1, 1024, 0, stream>>>(deg, dstoff, cur2, N);
  scatter_kernel<<<eb, 256, 0, stream>>>(src, dst, et, cntp, cursor, cur2, eidx, E, R);
  cvt_x_kernel<<<(N * D + 255) / 256, 256, 0, stream>>>(x, xb, N * D);
  cvt_w_kernel<<<(wtot + 255) / 256, 256, 0, stream>>>(W1, WT1, wtot);
  cvt_w_kernel<<<(wtot + 255) / 256, 256, 0, stream>>>(W2, WT2, wtot);

  // ---- layer 1 ----
  msg_kernel<<<msg_blocks, 256, 0, stream>>>(xb, WT1, eidx, msgp, nwaves);
  agg_kernel<<<agg_blocks, 256, 0, stream>>>(msgp, dstoff, agg, N);
  selfloop_kernel<<<sl_blocks, 256, 0, stream>>>(x, Wl1, agg, h, hb, N);

  // ---- layer 2 ----
  msg_kernel<<<msg_blocks, 256, 0, stream>>>(hb, WT2, eidx, msgp, nwaves);
  agg_kernel<<<agg_blocks, 256, 0, stream>>>(msgp, dstoff, agg, N);
  selfloop_kernel<<<sl_blocks, 256, 0, stream>>>(h, Wl2, agg, out, nullptr, N);
}

// Round 6
// 650.822 us; speedup vs baseline: 1.1219x; 1.0161x over previous
//
#include <hip/hip_runtime.h>

typedef __attribute__((ext_vector_type(8))) short bf16x8;
typedef __attribute__((ext_vector_type(4))) float f32x4;

#define RFL(v) __builtin_amdgcn_readfirstlane(v)

constexpr int D = 64;
constexpr int SEG = 64;   // relation-segment padding granule = edges per wave
constexpr int SL_K = 8;   // nodes per wave in selfloop kernel

__device__ inline unsigned short f2bf(float f) {  // RNE fp32->bf16
  unsigned u = __float_as_uint(f);
  u += 0x7fff + ((u >> 16) & 1);
  return (unsigned short)(u >> 16);
}
__device__ inline float bflo(unsigned u) { return __uint_as_float(u << 16); }
__device__ inline float bfhi(unsigned u) { return __uint_as_float(u & 0xffff0000u); }

// ---- counting: hist[rel] (LDS-batched), deg[dst] (L2-resident atomics) ----
__global__ __launch_bounds__(256) void count_kernel(
    const int* __restrict__ dst, const int* __restrict__ et,
    int* __restrict__ hist, int* __restrict__ deg, int E, int R) {
  __shared__ int lh[128];
  if ((int)threadIdx.x < R) lh[threadIdx.x] = 0;
  __syncthreads();
  int e = blockIdx.x * blockDim.x + threadIdx.x;
  if (e < E) {
    atomicAdd(&deg[dst[e]], 1);
    atomicAdd(&lh[et[e]], 1);
  }
  __syncthreads();
  if ((int)threadIdx.x < R) {
    int c = lh[threadIdx.x];
    if (c) atomicAdd(&hist[threadIdx.x], c);
  }
}

// ---- padded exclusive prefix over relations: cursor[r] ----
__global__ void prefix_kernel(const int* __restrict__ hist, int* __restrict__ cursor, int R) {
  __shared__ int sc[128];
  int l = threadIdx.x;
  int c = (l < R) ? ((hist[l] + SEG - 1) & ~(SEG - 1)) : 0;
  sc[l] = c;
  __syncthreads();
  for (int ofs = 1; ofs < 128; ofs <<= 1) {
    int v = (l >= ofs) ? sc[l - ofs] : 0;
    __syncthreads();
    sc[l] += v;
    __syncthreads();
  }
  if (l < R) cursor[l] = sc[l] - c;
}

// ---- exclusive scan over deg[0..N) -> dstoff (N+1) and working copy cur2 ----
__global__ __launch_bounds__(1024) void scan_deg_kernel(
    const int* __restrict__ deg, int* __restrict__ dstoff,
    int* __restrict__ cur2, int N) {
  __shared__ int ls[1024];
  const int T = 1024;
  int t = threadIdx.x;
  int K = (N + T - 1) / T;
  int beg = t * K, fin = min(beg + K, N);
  int s = 0;
  for (int i = beg; i < fin; ++i) s += deg[i];
  ls[t] = s;
  __syncthreads();
  for (int ofs = 1; ofs < T; ofs <<= 1) {
    int v = (t >= ofs) ? ls[t - ofs] : 0;
    __syncthreads();
    ls[t] += v;
    __syncthreads();
  }
  int run = (t == 0) ? 0 : ls[t - 1];
  for (int i = beg; i < fin; ++i) { dstoff[i] = run; cur2[i] = run; run += deg[i]; }
  if (t == 0) dstoff[N] = ls[T - 1];
}

// ---- counting-sort scatter: eidx[pos]={src,jd,rel,rel}; relrow[jd]=rel ----
// Pads stay 0xFF (jd = -1) from the memset.
__global__ __launch_bounds__(256) void scatter_kernel(
    const int* __restrict__ src, const int* __restrict__ dst, const int* __restrict__ et,
    int* __restrict__ cursor, int* __restrict__ cur2,
    int4* __restrict__ eidx, int* __restrict__ relrow, int E, int R) {
  __shared__ int lh[128];
  __shared__ int lbase[128];
  if ((int)threadIdx.x < R) lh[threadIdx.x] = 0;
  __syncthreads();
  int e = blockIdx.x * blockDim.x + threadIdx.x;
  int r = 0, lr = 0, s = 0, d = 0;
  bool valid = (e < E);
  if (valid) {
    r = et[e]; s = src[e]; d = dst[e];
    lr = atomicAdd(&lh[r], 1);
  }
  __syncthreads();
  if ((int)threadIdx.x < R) {
    int c = lh[threadIdx.x];
    if (c) lbase[threadIdx.x] = atomicAdd(&cursor[threadIdx.x], c);
  }
  __syncthreads();
  if (valid) {
    int pos = lbase[r] + lr;
    int jd = atomicAdd(&cur2[d], 1);          // dst-sorted msg row
    eidx[pos] = make_int4(s, jd, r, r);
    relrow[jd] = r;
  }
}

// ---- fp32 -> bf16 convert (node features) ----
__global__ __launch_bounds__(256) void cvt_x_kernel(
    const float* __restrict__ x, unsigned short* __restrict__ xb, int n) {
  int i = blockIdx.x * 256 + threadIdx.x;
  if (i < n) xb[i] = f2bf(x[i]);
}

// ---- W[r][k][n] fp32 -> WT[r][n][k] bf16 ----
__global__ __launch_bounds__(256) void cvt_w_kernel(
    const float* __restrict__ W, unsigned short* __restrict__ WT, int total) {
  int i = blockIdx.x * 256 + threadIdx.x;
  if (i >= total) return;
  int n = i & 63, k = (i >> 6) & 63, r = i >> 12;
  WT[(r << 12) + (n << 6) + k] = f2bf(W[(r << 12) + (k << 6) + n]);
}

// ---- Phase A: MFMA matvec, stream raw msgs (packed bf16, no atomics) ----
// msg row layout (32 dwords): dword o<16 = cols (o, o+16); o>=16 = cols (o+16, o+32).
__global__ __launch_bounds__(256) __attribute__((amdgpu_waves_per_eu(1, 4)))
void msg_kernel(const unsigned short* __restrict__ xb,
                const unsigned short* __restrict__ WT,
                const int4* __restrict__ eidx,
                unsigned int* __restrict__ msgp, int nwaves) {
  const int lane = (int)threadIdx.x & 63;
  const int l15 = lane & 15;
  const int q = lane >> 4;
  const int wave = blockIdx.x * 4 + ((int)threadIdx.x >> 6);
  if (wave >= nwaves) return;
  const long base = (long)wave * SEG;
  int r = RFL(eidx[base].w);                // wave-uniform relation
  if (r < 0) r = 0;                          // all-pad tail wave
  const unsigned short* wb = WT + ((long)r << 12);
  bf16x8 Bf[4][2];
#pragma unroll
  for (int nt = 0; nt < 4; ++nt)
#pragma unroll
    for (int kh = 0; kh < 2; ++kh)
      Bf[nt][kh] = *(const bf16x8*)(wb + (nt * 16 + l15) * 64 + kh * 32 + q * 8);
#pragma unroll
  for (int t = 0; t < 4; ++t) {
    int4 rec = eidx[base + t * 16 + l15];
    const unsigned short* xr = xb + ((long)max(rec.x, 0) << 6);
    bf16x8 A0 = *(const bf16x8*)(xr + q * 8);
    bf16x8 A1 = *(const bf16x8*)(xr + 32 + q * 8);
    f32x4 acc0 = (f32x4)0.0f, acc1 = (f32x4)0.0f, acc2 = (f32x4)0.0f, acc3 = (f32x4)0.0f;
    acc0 = __builtin_amdgcn_mfma_f32_16x16x32_bf16(A0, Bf[0][0], acc0, 0, 0, 0);
    acc0 = __builtin_amdgcn_mfma_f32_16x16x32_bf16(A1, Bf[0][1], acc0, 0, 0, 0);
    acc1 = __builtin_amdgcn_mfma_f32_16x16x32_bf16(A0, Bf[1][0], acc1, 0, 0, 0);
    acc1 = __builtin_amdgcn_mfma_f32_16x16x32_bf16(A1, Bf[1][1], acc1, 0, 0, 0);
    acc2 = __builtin_amdgcn_mfma_f32_16x16x32_bf16(A0, Bf[2][0], acc2, 0, 0, 0);
    acc2 = __builtin_amdgcn_mfma_f32_16x16x32_bf16(A1, Bf[2][1], acc2, 0, 0, 0);
    acc3 = __builtin_amdgcn_mfma_f32_16x16x32_bf16(A0, Bf[3][0], acc3, 0, 0, 0);
    acc3 = __builtin_amdgcn_mfma_f32_16x16x32_bf16(A1, Bf[3][1], acc3, 0, 0, 0);
#pragma unroll
    for (int rg = 0; rg < 4; ++rg) {
      int row = q * 4 + rg;                  // C/D row = edge within tile
      int jd = __shfl(rec.y, row);           // dst-sorted msg row id (-1 = pad)
      if (jd >= 0) {
        unsigned p0 = (unsigned)f2bf(acc0[rg]) | ((unsigned)f2bf(acc1[rg]) << 16);
        unsigned p1 = (unsigned)f2bf(acc2[rg]) | ((unsigned)f2bf(acc3[rg]) << 16);
        unsigned int* mp = msgp + (long)jd * 32;
        mp[l15] = p0;
        mp[16 + l15] = p1;
      }
    }
  }
}

// ---- Phase B: wave per dst; per-(dst,rel) counts derived locally in LDS ----
__global__ __launch_bounds__(256) void agg_kernel(
    const unsigned int* __restrict__ msgp, const int* __restrict__ dstoff,
    const int* __restrict__ relrow, float* __restrict__ agg, int N) {
  __shared__ int rsh[4][256];
  __shared__ float fsh[4][256];
  const int wv = (int)threadIdx.x >> 6;
  const int lane = (int)threadIdx.x & 63;
  const int j = lane & 31;
  const int half = lane >> 5;
  const int d = blockIdx.x * 4 + wv;
  if (d >= N) return;
  const int off = dstoff[d], end = dstoff[d + 1];
  const int deg = end - off;
  float aLo = 0.f, aHi = 0.f;
  if (deg > 0 && deg <= 256) {
    // stage rel values; count equal-rel matches -> weight 1/cnt
    const int nit = (deg + 63) >> 6;
    int cl[4];
    for (int it = 0; it < nit; ++it) {
      int l = it * 64 + lane;
      if (l < deg) rsh[wv][l] = relrow[off + l];
    }
    __threadfence_block();
    for (int it = 0; it < nit; ++it) {
      int l = it * 64 + lane;
      if (l < deg) {
        int rv = rsh[wv][l];
        int c = 0;
        for (int m = 0; m < deg; ++m) c += (rsh[wv][m] == rv) ? 1 : 0;
        cl[it] = c;
      }
    }
    for (int it = 0; it < nit; ++it) {
      int l = it * 64 + lane;
      if (l < deg) fsh[wv][l] = 1.0f / (float)cl[it];
    }
    __threadfence_block();
    float a0 = 0.f, a1 = 0.f, b0 = 0.f, b1 = 0.f;
    int i = off + half;
    for (; i + 2 < end; i += 4) {
      float w0 = fsh[wv][i - off];
      float w1 = fsh[wv][i + 2 - off];
      unsigned u0 = msgp[(long)i * 32 + j];
      unsigned u1 = msgp[(long)(i + 2) * 32 + j];
      a0 = fmaf(w0, bflo(u0), a0);
      a1 = fmaf(w0, bfhi(u0), a1);
      b0 = fmaf(w1, bflo(u1), b0);
      b1 = fmaf(w1, bfhi(u1), b1);
    }
    if (i < end) {
      float w0 = fsh[wv][i - off];
      unsigned u0 = msgp[(long)i * 32 + j];
      a0 = fmaf(w0, bflo(u0), a0);
      a1 = fmaf(w0, bfhi(u0), a1);
    }
    aLo = a0 + b0;
    aHi = a1 + b1;
  } else if (deg > 256) {
    // huge-degree fallback (correct for any input; effectively never runs)
    for (int i = off + half; i < end; i += 2) {
      int rv = relrow[i];
      int c = 0;
      for (int m = off; m < end; ++m) c += (relrow[m] == rv) ? 1 : 0;
      float w = 1.0f / (float)c;
      unsigned u0 = msgp[(long)i * 32 + j];
      aLo = fmaf(w, bflo(u0), aLo);
      aHi = fmaf(w, bfhi(u0), aHi);
    }
  }
  aLo += __shfl_xor(aLo, 32);
  aHi += __shfl_xor(aHi, 32);
  if (half == 0) {
    int colLo = (j < 16) ? j : j + 16;       // cols {0..15, 32..47}
    agg[(long)d * D + colLo] = aLo;
    agg[(long)d * D + colLo + 16] = aHi;     // cols {16..31, 48..63}
  }
}

// ---- out = relu(agg + x @ Wl) (exact fp32), optionally emit bf16 copy ----
#define REP16(M) M(0) M(1) M(2) M(3) M(4) M(5) M(6) M(7) \
                 M(8) M(9) M(10) M(11) M(12) M(13) M(14) M(15)
#define W_DECL(i) float4 wq##i;
#define W_LOAD(i) wq##i = make_float4(wp[(4*i+0)*64], wp[(4*i+1)*64], \
                                      wp[(4*i+2)*64], wp[(4*i+3)*64]);
#define W_FMA(i)  { float4 xv = xr[i]; \
    acc0 = fmaf(xv.x, wq##i.x, acc0); acc1 = fmaf(xv.y, wq##i.y, acc1); \
    acc0 = fmaf(xv.z, wq##i.z, acc0); acc1 = fmaf(xv.w, wq##i.w, acc1); }

__global__ __launch_bounds__(256) __attribute__((amdgpu_waves_per_eu(1, 4)))
void selfloop_kernel(const float* __restrict__ x, const float* __restrict__ Wl,
                     const float* __restrict__ agg, float* __restrict__ out,
                     unsigned short* __restrict__ hb, int N) {
  const int lane = (int)threadIdx.x & 63;
  const int wave = blockIdx.x * 4 + ((int)threadIdx.x >> 6);
  long base = (long)wave * SL_K;
  if (base >= N) return;
  long end = base + SL_K;
  if (end > N) end = N;
  const float* wp = Wl + lane;
  REP16(W_DECL)
  REP16(W_LOAD)
  for (long n = base; n < end; ++n) {
    float acc0 = agg[n * D + lane], acc1 = 0.f;
    const float4* xr = (const float4*)(x + n * D);
    REP16(W_FMA)
    float v = fmaxf(acc0 + acc1, 0.0f);
    out[n * D + lane] = v;
    if (hb) hb[n * D + lane] = f2bf(v);
  }
}

extern "C" void kernel_launch(void* const* d_in, const int* in_sizes, int n_in,
                              void* d_out, int out_size, void* d_ws, size_t ws_size,
                              hipStream_t stream) {
  const float* x   = (const float*)d_in[0];
  const int* src   = (const int*)d_in[1];
  const int* dst   = (const int*)d_in[2];
  const int* et    = (const int*)d_in[3];
  const float* W1  = (const float*)d_in[4];
  const float* Wl1 = (const float*)d_in[5];
  const float* W2  = (const float*)d_in[6];
  const float* Wl2 = (const float*)d_in[7];
  float* out = (float*)d_out;

  const int N = in_sizes[0] / D;
  const int E = in_sizes[1];
  const int R = in_sizes[4] / (D * D);

  const int Ecap = ((E + SEG - 1) & ~(SEG - 1)) + R * SEG;
  const int nwaves = Ecap / SEG;

  char* ws = (char*)d_ws;
  size_t off = 0;
  auto alloc = [&](size_t bytes) -> void* {
    void* p = (void*)(ws + off);
    off += (bytes + 255) & ~(size_t)255;
    return p;
  };
  int*   hist   = (int*)alloc((size_t)R * sizeof(int));
  int*   cursor = (int*)alloc((size_t)R * sizeof(int));
  int*   deg    = (int*)alloc((size_t)N * sizeof(int));
  int*   dstoff = (int*)alloc((size_t)(N + 1) * sizeof(int));
  int*   cur2   = (int*)alloc((size_t)N * sizeof(int));
  int*   relrow = (int*)alloc((size_t)E * sizeof(int));
  int4*  eidx   = (int4*)alloc((size_t)(Ecap + SEG) * sizeof(int4));
  unsigned int* msgp = (unsigned int*)alloc((size_t)E * 32 * sizeof(unsigned int));
  float* agg    = (float*)alloc((size_t)N * D * sizeof(float));
  float* h      = (float*)alloc((size_t)N * D * sizeof(float));
  unsigned short* xb  = (unsigned short*)alloc((size_t)N * D * sizeof(unsigned short));
  unsigned short* hb  = (unsigned short*)alloc((size_t)N * D * sizeof(unsigned short));
  unsigned short* WT1 = (unsigned short*)alloc((size_t)R * D * D * sizeof(unsigned short));
  unsigned short* WT2 = (unsigned short*)alloc((size_t)R * D * D * sizeof(unsigned short));
  (void)ws_size; (void)n_in; (void)out_size;

  const int eb = (E + 255) / 256;
  const int msg_blocks = (nwaves + 3) / 4;
  const int agg_blocks = (N + 3) / 4;
  const int sl_waves = (N + SL_K - 1) / SL_K;
  const int sl_blocks = (sl_waves + 3) / 4;
  const int wtot = R * D * D;

  // ---- shared preprocessing ----
  hipMemsetAsync(hist, 0, (size_t)R * sizeof(int), stream);
  hipMemsetAsync(deg, 0, (size_t)N * sizeof(int), stream);
  hipMemsetAsync(eidx, 0xFF, (size_t)(Ecap + SEG) * sizeof(int4), stream);
  count_kernel<<<eb, 256, 0, stream>>>(dst, et, hist, deg, E, R);
  prefix_kernel<<<1, 128, 0, stream>>>(hist, cursor, R);
  scan_deg_kernel<<<1, 1024, 0, stream>>>(deg, dstoff, cur2, N);
  scatter_kernel<<<eb, 256, 0, stream>>>(src, dst, et, cursor, cur2, eidx, relrow, E, R);
  cvt_x_kernel<<<(N * D + 255) / 256, 256, 0, stream>>>(x, xb, N * D);
  cvt_w_kernel<<<(wtot + 255) / 256, 256, 0, stream>>>(W1, WT1, wtot);
  cvt_w_kernel<<<(wtot + 255) / 256, 256, 0, stream>>>(W2, WT2, wtot);

  // ---- layer 1 ----
  msg_kernel<<<msg_blocks, 256, 0, stream>>>(xb, WT1, eidx, msgp, nwaves);
  agg_kernel<<<agg_blocks, 256, 0, stream>>>(msgp, dstoff, relrow, agg, N);
  selfloop_kernel<<<sl_blocks, 256, 0, stream>>>(x, Wl1, agg, h, hb, N);

  // ---- layer 2 ----
  msg_kernel<<<msg_blocks, 256, 0, stream>>>(hb, WT2, eidx, msgp, nwaves);
  agg_kernel<<<agg_blocks, 256, 0, stream>>>(msgp, dstoff, relrow, agg, N);
  selfloop_kernel<<<sl_blocks, 256, 0, stream>>>(h, Wl2, agg, out, nullptr, N);
}

// Round 7
// 547.345 us; speedup vs baseline: 1.3340x; 1.1891x over previous
//
#include <hip/hip_runtime.h>

typedef __attribute__((ext_vector_type(8))) short bf16x8;
typedef __attribute__((ext_vector_type(4))) float f32x4;

#define RFL(v) __builtin_amdgcn_readfirstlane(v)

constexpr int D = 64;
constexpr int SEG = 64;   // relation-segment padding granule = edges per wave
constexpr int SL_K = 8;   // nodes per wave in selfloop kernel

__device__ inline unsigned short f2bf(float f) {  // RNE fp32->bf16
  unsigned u = __float_as_uint(f);
  u += 0x7fff + ((u >> 16) & 1);
  return (unsigned short)(u >> 16);
}
__device__ inline float bflo(unsigned u) { return __uint_as_float(u << 16); }
__device__ inline float bfhi(unsigned u) { return __uint_as_float(u & 0xffff0000u); }

// ---- counting: hist[rel] (LDS-batched), deg[dst] (L2-resident atomics) ----
__global__ __launch_bounds__(256) void count_kernel(
    const int* __restrict__ dst, const int* __restrict__ et,
    int* __restrict__ hist, int* __restrict__ deg, int E, int R) {
  __shared__ int lh[128];
  if ((int)threadIdx.x < R) lh[threadIdx.x] = 0;
  __syncthreads();
  int e = blockIdx.x * blockDim.x + threadIdx.x;
  if (e < E) {
    atomicAdd(&deg[dst[e]], 1);
    atomicAdd(&lh[et[e]], 1);
  }
  __syncthreads();
  if ((int)threadIdx.x < R) {
    int c = lh[threadIdx.x];
    if (c) atomicAdd(&hist[threadIdx.x], c);
  }
}

// ---- padded exclusive prefix over relations: cursor[r] ----
__global__ void prefix_kernel(const int* __restrict__ hist, int* __restrict__ cursor, int R) {
  __shared__ int sc[128];
  int l = threadIdx.x;
  int c = (l < R) ? ((hist[l] + SEG - 1) & ~(SEG - 1)) : 0;
  sc[l] = c;
  __syncthreads();
  for (int ofs = 1; ofs < 128; ofs <<= 1) {
    int v = (l >= ofs) ? sc[l - ofs] : 0;
    __syncthreads();
    sc[l] += v;
    __syncthreads();
  }
  if (l < R) cursor[l] = sc[l] - c;
}

// ---- multi-block exclusive scan of deg: A) block sums, B) scan sums, C) rescan ----
__global__ __launch_bounds__(256) void scanA_kernel(
    const int* __restrict__ deg, int* __restrict__ bsum, int N) {
  __shared__ int s[256];
  int t = threadIdx.x;
  int i = blockIdx.x * 256 + t;
  s[t] = (i < N) ? deg[i] : 0;
  __syncthreads();
  for (int o = 128; o > 0; o >>= 1) {
    if (t < o) s[t] += s[t + o];
    __syncthreads();
  }
  if (t == 0) bsum[blockIdx.x] = s[0];
}

__global__ __launch_bounds__(256) void scanB_kernel(int* __restrict__ bsum, int nb) {
  // single block; tile-looped exclusive scan with running carry (general nb)
  __shared__ int s[256];
  __shared__ int carry;
  int t = threadIdx.x;
  if (t == 0) carry = 0;
  __syncthreads();
  for (int base = 0; base < nb; base += 256) {
    int i = base + t;
    int v = (i < nb) ? bsum[i] : 0;
    s[t] = v;
    __syncthreads();
    for (int o = 1; o < 256; o <<= 1) {
      int u = (t >= o) ? s[t - o] : 0;
      __syncthreads();
      s[t] += u;
      __syncthreads();
    }
    if (i < nb) bsum[i] = carry + s[t] - v;   // exclusive
    __syncthreads();
    if (t == 0) carry += s[255];
    __syncthreads();
  }
}

__global__ __launch_bounds__(256) void scanC_kernel(
    const int* __restrict__ deg, const int* __restrict__ bsum,
    int* __restrict__ dstoff, int* __restrict__ cur2, int N) {
  __shared__ int s[256];
  int t = threadIdx.x;
  int i = blockIdx.x * 256 + t;
  int v = (i < N) ? deg[i] : 0;
  s[t] = v;
  __syncthreads();
  for (int o = 1; o < 256; o <<= 1) {
    int u = (t >= o) ? s[t - o] : 0;
    __syncthreads();
    s[t] += u;
    __syncthreads();
  }
  int excl = bsum[blockIdx.x] + s[t] - v;
  if (i < N) { dstoff[i] = excl; cur2[i] = excl; }
  if (i == N - 1) dstoff[N] = excl + v;
}

// ---- counting-sort scatter: eidx[pos]={src,jd,rel,rel}; relrow[jd]=rel ----
// Pads stay 0xFF (jd = -1) from the memset.
__global__ __launch_bounds__(256) void scatter_kernel(
    const int* __restrict__ src, const int* __restrict__ dst, const int* __restrict__ et,
    int* __restrict__ cursor, int* __restrict__ cur2,
    int4* __restrict__ eidx, int* __restrict__ relrow, int E, int R) {
  __shared__ int lh[128];
  __shared__ int lbase[128];
  if ((int)threadIdx.x < R) lh[threadIdx.x] = 0;
  __syncthreads();
  int e = blockIdx.x * blockDim.x + threadIdx.x;
  int r = 0, lr = 0, s = 0, d = 0;
  bool valid = (e < E);
  if (valid) {
    r = et[e]; s = src[e]; d = dst[e];
    lr = atomicAdd(&lh[r], 1);
  }
  __syncthreads();
  if ((int)threadIdx.x < R) {
    int c = lh[threadIdx.x];
    if (c) lbase[threadIdx.x] = atomicAdd(&cursor[threadIdx.x], c);
  }
  __syncthreads();
  if (valid) {
    int pos = lbase[r] + lr;
    int jd = atomicAdd(&cur2[d], 1);          // dst-sorted msg row
    eidx[pos] = make_int4(s, jd, r, r);
    relrow[jd] = r;
  }
}

// ---- fp32 -> bf16 convert (node features) ----
__global__ __launch_bounds__(256) void cvt_x_kernel(
    const float* __restrict__ x, unsigned short* __restrict__ xb, int n) {
  int i = blockIdx.x * 256 + threadIdx.x;
  if (i < n) xb[i] = f2bf(x[i]);
}

// ---- W[r][k][n] fp32 -> WT[r][n][k] bf16 ----
__global__ __launch_bounds__(256) void cvt_w_kernel(
    const float* __restrict__ W, unsigned short* __restrict__ WT, int total) {
  int i = blockIdx.x * 256 + threadIdx.x;
  if (i >= total) return;
  int n = i & 63, k = (i >> 6) & 63, r = i >> 12;
  WT[(r << 12) + (n << 6) + k] = f2bf(W[(r << 12) + (k << 6) + n]);
}

// ---- Phase A: MFMA matvec, stream raw msgs (packed bf16, no atomics) ----
// msg row layout (32 dwords): dword o<16 = cols (o, o+16); o>=16 = cols (o+16, o+32).
__global__ __launch_bounds__(256) __attribute__((amdgpu_waves_per_eu(1, 4)))
void msg_kernel(const unsigned short* __restrict__ xb,
                const unsigned short* __restrict__ WT,
                const int4* __restrict__ eidx,
                unsigned int* __restrict__ msgp, int nwaves) {
  const int lane = (int)threadIdx.x & 63;
  const int l15 = lane & 15;
  const int q = lane >> 4;
  const int wave = blockIdx.x * 4 + ((int)threadIdx.x >> 6);
  if (wave >= nwaves) return;
  const long base = (long)wave * SEG;
  int r = RFL(eidx[base].w);                // wave-uniform relation
  if (r < 0) r = 0;                          // all-pad tail wave
  const unsigned short* wb = WT + ((long)r << 12);
  bf16x8 Bf[4][2];
#pragma unroll
  for (int nt = 0; nt < 4; ++nt)
#pragma unroll
    for (int kh = 0; kh < 2; ++kh)
      Bf[nt][kh] = *(const bf16x8*)(wb + (nt * 16 + l15) * 64 + kh * 32 + q * 8);
#pragma unroll
  for (int t = 0; t < 4; ++t) {
    int4 rec = eidx[base + t * 16 + l15];
    const unsigned short* xr = xb + ((long)max(rec.x, 0) << 6);
    bf16x8 A0 = *(const bf16x8*)(xr + q * 8);
    bf16x8 A1 = *(const bf16x8*)(xr + 32 + q * 8);
    f32x4 acc0 = (f32x4)0.0f, acc1 = (f32x4)0.0f, acc2 = (f32x4)0.0f, acc3 = (f32x4)0.0f;
    acc0 = __builtin_amdgcn_mfma_f32_16x16x32_bf16(A0, Bf[0][0], acc0, 0, 0, 0);
    acc0 = __builtin_amdgcn_mfma_f32_16x16x32_bf16(A1, Bf[0][1], acc0, 0, 0, 0);
    acc1 = __builtin_amdgcn_mfma_f32_16x16x32_bf16(A0, Bf[1][0], acc1, 0, 0, 0);
    acc1 = __builtin_amdgcn_mfma_f32_16x16x32_bf16(A1, Bf[1][1], acc1, 0, 0, 0);
    acc2 = __builtin_amdgcn_mfma_f32_16x16x32_bf16(A0, Bf[2][0], acc2, 0, 0, 0);
    acc2 = __builtin_amdgcn_mfma_f32_16x16x32_bf16(A1, Bf[2][1], acc2, 0, 0, 0);
    acc3 = __builtin_amdgcn_mfma_f32_16x16x32_bf16(A0, Bf[3][0], acc3, 0, 0, 0);
    acc3 = __builtin_amdgcn_mfma_f32_16x16x32_bf16(A1, Bf[3][1], acc3, 0, 0, 0);
#pragma unroll
    for (int rg = 0; rg < 4; ++rg) {
      int row = q * 4 + rg;                  // C/D row = edge within tile
      int jd = __shfl(rec.y, row);           // dst-sorted msg row id (-1 = pad)
      if (jd >= 0) {
        unsigned p0 = (unsigned)f2bf(acc0[rg]) | ((unsigned)f2bf(acc1[rg]) << 16);
        unsigned p1 = (unsigned)f2bf(acc2[rg]) | ((unsigned)f2bf(acc3[rg]) << 16);
        unsigned int* mp = msgp + (long)jd * 32;
        mp[l15] = p0;
        mp[16 + l15] = p1;
      }
    }
  }
}

// ---- Phase B: wave per dst; per-(dst,rel) counts derived locally in LDS ----
__global__ __launch_bounds__(256) void agg_kernel(
    const unsigned int* __restrict__ msgp, const int* __restrict__ dstoff,
    const int* __restrict__ relrow, float* __restrict__ agg, int N) {
  __shared__ int rsh[4][256];
  __shared__ float fsh[4][256];
  const int wv = (int)threadIdx.x >> 6;
  const int lane = (int)threadIdx.x & 63;
  const int j = lane & 31;
  const int half = lane >> 5;
  const int d = blockIdx.x * 4 + wv;
  if (d >= N) return;
  const int off = dstoff[d], end = dstoff[d + 1];
  const int deg = end - off;
  float aLo = 0.f, aHi = 0.f;
  if (deg > 0 && deg <= 256) {
    const int nit = (deg + 63) >> 6;
    int cl[4];
    for (int it = 0; it < nit; ++it) {
      int l = it * 64 + lane;
      if (l < deg) rsh[wv][l] = relrow[off + l];
    }
    __threadfence_block();
    for (int it = 0; it < nit; ++it) {
      int l = it * 64 + lane;
      if (l < deg) {
        int rv = rsh[wv][l];
        int c = 0;
        for (int m = 0; m < deg; ++m) c += (rsh[wv][m] == rv) ? 1 : 0;
        cl[it] = c;
      }
    }
    for (int it = 0; it < nit; ++it) {
      int l = it * 64 + lane;
      if (l < deg) fsh[wv][l] = 1.0f / (float)cl[it];
    }
    __threadfence_block();
    float a0 = 0.f, a1 = 0.f, b0 = 0.f, b1 = 0.f;
    int i = off + half;
    for (; i + 2 < end; i += 4) {
      float w0 = fsh[wv][i - off];
      float w1 = fsh[wv][i + 2 - off];
      unsigned u0 = msgp[(long)i * 32 + j];
      unsigned u1 = msgp[(long)(i + 2) * 32 + j];
      a0 = fmaf(w0, bflo(u0), a0);
      a1 = fmaf(w0, bfhi(u0), a1);
      b0 = fmaf(w1, bflo(u1), b0);
      b1 = fmaf(w1, bfhi(u1), b1);
    }
    if (i < end) {
      float w0 = fsh[wv][i - off];
      unsigned u0 = msgp[(long)i * 32 + j];
      a0 = fmaf(w0, bflo(u0), a0);
      a1 = fmaf(w0, bfhi(u0), a1);
    }
    aLo = a0 + b0;
    aHi = a1 + b1;
  } else if (deg > 256) {
    for (int i = off + half; i < end; i += 2) {
      int rv = relrow[i];
      int c = 0;
      for (int m = off; m < end; ++m) c += (relrow[m] == rv) ? 1 : 0;
      float w = 1.0f / (float)c;
      unsigned u0 = msgp[(long)i * 32 + j];
      aLo = fmaf(w, bflo(u0), aLo);
      aHi = fmaf(w, bfhi(u0), aHi);
    }
  }
  aLo += __shfl_xor(aLo, 32);
  aHi += __shfl_xor(aHi, 32);
  if (half == 0) {
    int colLo = (j < 16) ? j : j + 16;       // cols {0..15, 32..47}
    agg[(long)d * D + colLo] = aLo;
    agg[(long)d * D + colLo + 16] = aHi;     // cols {16..31, 48..63}
  }
}

// ---- out = relu(agg + x @ Wl) (exact fp32), optionally emit bf16 copy ----
#define REP16(M) M(0) M(1) M(2) M(3) M(4) M(5) M(6) M(7) \
                 M(8) M(9) M(10) M(11) M(12) M(13) M(14) M(15)
#define W_DECL(i) float4 wq##i;
#define W_LOAD(i) wq##i = make_float4(wp[(4*i+0)*64], wp[(4*i+1)*64], \
                                      wp[(4*i+2)*64], wp[(4*i+3)*64]);
#define W_FMA(i)  { float4 xv = xr[i]; \
    acc0 = fmaf(xv.x, wq##i.x, acc0); acc1 = fmaf(xv.y, wq##i.y, acc1); \
    acc0 = fmaf(xv.z, wq##i.z, acc0); acc1 = fmaf(xv.w, wq##i.w, acc1); }

__global__ __launch_bounds__(256) __attribute__((amdgpu_waves_per_eu(1, 4)))
void selfloop_kernel(const float* __restrict__ x, const float* __restrict__ Wl,
                     const float* __restrict__ agg, float* __restrict__ out,
                     unsigned short* __restrict__ hb, int N) {
  const int lane = (int)threadIdx.x & 63;
  const int wave = blockIdx.x * 4 + ((int)threadIdx.x >> 6);
  long base = (long)wave * SL_K;
  if (base >= N) return;
  long end = base + SL_K;
  if (end > N) end = N;
  const float* wp = Wl + lane;
  REP16(W_DECL)
  REP16(W_LOAD)
  for (long n = base; n < end; ++n) {
    float acc0 = agg[n * D + lane], acc1 = 0.f;
    const float4* xr = (const float4*)(x + n * D);
    REP16(W_FMA)
    float v = fmaxf(acc0 + acc1, 0.0f);
    out[n * D + lane] = v;
    if (hb) hb[n * D + lane] = f2bf(v);
  }
}

extern "C" void kernel_launch(void* const* d_in, const int* in_sizes, int n_in,
                              void* d_out, int out_size, void* d_ws, size_t ws_size,
                              hipStream_t stream) {
  const float* x   = (const float*)d_in[0];
  const int* src   = (const int*)d_in[1];
  const int* dst   = (const int*)d_in[2];
  const int* et    = (const int*)d_in[3];
  const float* W1  = (const float*)d_in[4];
  const float* Wl1 = (const float*)d_in[5];
  const float* W2  = (const float*)d_in[6];
  const float* Wl2 = (const float*)d_in[7];
  float* out = (float*)d_out;

  const int N = in_sizes[0] / D;
  const int E = in_sizes[1];
  const int R = in_sizes[4] / (D * D);

  const int Ecap = ((E + SEG - 1) & ~(SEG - 1)) + R * SEG;
  const int nwaves = Ecap / SEG;
  const int nb = (N + 255) / 256;

  char* ws = (char*)d_ws;
  size_t off = 0;
  auto alloc = [&](size_t bytes) -> void* {
    void* p = (void*)(ws + off);
    off += (bytes + 255) & ~(size_t)255;
    return p;
  };
  int*   hist   = (int*)alloc((size_t)R * sizeof(int));
  int*   cursor = (int*)alloc((size_t)R * sizeof(int));
  int*   deg    = (int*)alloc((size_t)N * sizeof(int));
  int*   bsum   = (int*)alloc((size_t)nb * sizeof(int));
  int*   dstoff = (int*)alloc((size_t)(N + 1) * sizeof(int));
  int*   cur2   = (int*)alloc((size_t)N * sizeof(int));
  int*   relrow = (int*)alloc((size_t)E * sizeof(int));
  int4*  eidx   = (int4*)alloc((size_t)(Ecap + SEG) * sizeof(int4));
  unsigned int* msgp = (unsigned int*)alloc((size_t)E * 32 * sizeof(unsigned int));
  float* agg    = (float*)alloc((size_t)N * D * sizeof(float));
  float* h      = (float*)alloc((size_t)N * D * sizeof(float));
  unsigned short* xb  = (unsigned short*)alloc((size_t)N * D * sizeof(unsigned short));
  unsigned short* hb  = (unsigned short*)alloc((size_t)N * D * sizeof(unsigned short));
  unsigned short* WT1 = (unsigned short*)alloc((size_t)R * D * D * sizeof(unsigned short));
  unsigned short* WT2 = (unsigned short*)alloc((size_t)R * D * D * sizeof(unsigned short));
  (void)ws_size; (void)n_in; (void)out_size;

  const int eb = (E + 255) / 256;
  const int msg_blocks = (nwaves + 3) / 4;
  const int agg_blocks = (N + 3) / 4;
  const int sl_waves = (N + SL_K - 1) / SL_K;
  const int sl_blocks = (sl_waves + 3) / 4;
  const int wtot = R * D * D;

  // ---- shared preprocessing ----
  hipMemsetAsync(hist, 0, (size_t)R * sizeof(int), stream);
  hipMemsetAsync(deg, 0, (size_t)N * sizeof(int), stream);
  hipMemsetAsync(eidx, 0xFF, (size_t)(Ecap + SEG) * sizeof(int4), stream);
  count_kernel<<<eb, 256, 0, stream>>>(dst, et, hist, deg, E, R);
  prefix_kernel<<<1, 128, 0, stream>>>(hist, cursor, R);
  scanA_kernel<<<nb, 256, 0, stream>>>(deg, bsum, N);
  scanB_kernel<<<1, 256, 0, stream>>>(bsum, nb);
  scanC_kernel<<<nb, 256, 0, stream>>>(deg, bsum, dstoff, cur2, N);
  scatter_kernel<<<eb, 256, 0, stream>>>(src, dst, et, cursor, cur2, eidx, relrow, E, R);
  cvt_x_kernel<<<(N * D + 255) / 256, 256, 0, stream>>>(x, xb, N * D);
  cvt_w_kernel<<<(wtot + 255) / 256, 256, 0, stream>>>(W1, WT1, wtot);
  cvt_w_kernel<<<(wtot + 255) / 256, 256, 0, stream>>>(W2, WT2, wtot);

  // ---- layer 1 ----
  msg_kernel<<<msg_blocks, 256, 0, stream>>>(xb, WT1, eidx, msgp, nwaves);
  agg_kernel<<<agg_blocks, 256, 0, stream>>>(msgp, dstoff, relrow, agg, N);
  selfloop_kernel<<<sl_blocks, 256, 0, stream>>>(x, Wl1, agg, h, hb, N);

  // ---- layer 2 ----
  msg_kernel<<<msg_blocks, 256, 0, stream>>>(hb, WT2, eidx, msgp, nwaves);
  agg_kernel<<<agg_blocks, 256, 0, stream>>>(msgp, dstoff, relrow, agg, N);
  selfloop_kernel<<<sl_blocks, 256, 0, stream>>>(h, Wl2, agg, out, nullptr, N);
}

// Round 8
// 469.342 us; speedup vs baseline: 1.5557x; 1.1662x over previous
//
#include <hip/hip_runtime.h>

typedef __attribute__((ext_vector_type(8))) short bf16x8;
typedef __attribute__((ext_vector_type(4))) float f32x4;

#define RFL(v) __builtin_amdgcn_readfirstlane(v)

constexpr int D = 64;
constexpr int SEG = 64;   // relation-segment padding granule = edges per wave
constexpr int SL_K = 8;   // nodes per wave in selfloop kernel

__device__ inline unsigned short f2bf(float f) {  // RNE fp32->bf16
  unsigned u = __float_as_uint(f);
  u += 0x7fff + ((u >> 16) & 1);
  return (unsigned short)(u >> 16);
}
__device__ inline float bflo(unsigned u) { return __uint_as_float(u << 16); }
__device__ inline float bfhi(unsigned u) { return __uint_as_float(u & 0xffff0000u); }

// ---- counting: per-block relation histogram -> bcnt[r*nbE+b]; deg atomics ----
__global__ __launch_bounds__(256) void count_kernel(
    const int* __restrict__ dst, const int* __restrict__ et,
    int* __restrict__ bcnt, int* __restrict__ deg, int E, int R, int nbE) {
  __shared__ int lh[128];
  int t = threadIdx.x;
  if (t < 128) lh[t] = 0;
  __syncthreads();
  int e = blockIdx.x * 256 + t;
  if (e < E) {
    atomicAdd(&deg[dst[e]], 1);
    atomicAdd(&lh[et[e]], 1);
  }
  __syncthreads();
  if (t < R) bcnt[t * nbE + blockIdx.x] = lh[t];  // no global hist atomics
}

// ---- generic 3-phase exclusive scan: A) block sums, B) scan sums, C) rescan ----
__global__ __launch_bounds__(256) void scanA_kernel(
    const int* __restrict__ arr, int* __restrict__ bsum, int n) {
  __shared__ int s[256];
  int t = threadIdx.x;
  int i = blockIdx.x * 256 + t;
  s[t] = (i < n) ? arr[i] : 0;
  __syncthreads();
  for (int o = 128; o > 0; o >>= 1) {
    if (t < o) s[t] += s[t + o];
    __syncthreads();
  }
  if (t == 0) bsum[blockIdx.x] = s[0];
}

__global__ __launch_bounds__(256) void scanB_kernel(int* __restrict__ bsum, int nb) {
  __shared__ int s[256];
  __shared__ int carry;
  int t = threadIdx.x;
  if (t == 0) carry = 0;
  __syncthreads();
  for (int base = 0; base < nb; base += 256) {
    int i = base + t;
    int v = (i < nb) ? bsum[i] : 0;
    s[t] = v;
    __syncthreads();
    for (int o = 1; o < 256; o <<= 1) {
      int u = (t >= o) ? s[t - o] : 0;
      __syncthreads();
      s[t] += u;
      __syncthreads();
    }
    if (i < nb) bsum[i] = carry + s[t] - v;   // exclusive
    __syncthreads();
    if (t == 0) carry += s[255];
    __syncthreads();
  }
}

// writes pref[i] (exclusive) and pref[n] = total
__global__ __launch_bounds__(256) void scanC_pref_kernel(
    const int* __restrict__ arr, const int* __restrict__ bsum,
    int* __restrict__ pref, int n) {
  __shared__ int s[256];
  int t = threadIdx.x;
  int i = blockIdx.x * 256 + t;
  int v = (i < n) ? arr[i] : 0;
  s[t] = v;
  __syncthreads();
  for (int o = 1; o < 256; o <<= 1) {
    int u = (t >= o) ? s[t - o] : 0;
    __syncthreads();
    s[t] += u;
    __syncthreads();
  }
  int excl = bsum[blockIdx.x] + s[t] - v;
  if (i < n) pref[i] = excl;
  if (i == n - 1) pref[n] = excl + v;
}

// deg variant: writes dstoff (N+1) and working copy cur2
__global__ __launch_bounds__(256) void scanC_deg_kernel(
    const int* __restrict__ deg, const int* __restrict__ bsum,
    int* __restrict__ dstoff, int* __restrict__ cur2, int N) {
  __shared__ int s[256];
  int t = threadIdx.x;
  int i = blockIdx.x * 256 + t;
  int v = (i < N) ? deg[i] : 0;
  s[t] = v;
  __syncthreads();
  for (int o = 1; o < 256; o <<= 1) {
    int u = (t >= o) ? s[t - o] : 0;
    __syncthreads();
    s[t] += u;
    __syncthreads();
  }
  int excl = bsum[blockIdx.x] + s[t] - v;
  if (i < N) { dstoff[i] = excl; cur2[i] = excl; }
  if (i == N - 1) dstoff[N] = excl + v;
}

// ---- padded relation cursors from bcnt-scan boundary values ----
__global__ void prefix_kernel(const int* __restrict__ prefE,
                              int* __restrict__ cursor, int nbE, int R) {
  __shared__ int sc[128];
  int l = threadIdx.x;
  int c = 0;
  if (l < R) {
    int tot = prefE[(l + 1) * nbE] - prefE[l * nbE];
    c = (tot + SEG - 1) & ~(SEG - 1);
  }
  sc[l] = c;
  __syncthreads();
  for (int ofs = 1; ofs < 128; ofs <<= 1) {
    int v = (l >= ofs) ? sc[l - ofs] : 0;
    __syncthreads();
    sc[l] += v;
    __syncthreads();
  }
  if (l < R) cursor[l] = sc[l] - c;
}

// ---- counting-sort scatter: block bases precomputed (no cursor atomics) ----
// eidx[pos]={src,jd,rel,rel}; relrow[jd]=rel. Pads stay 0xFF (jd=-1).
__global__ __launch_bounds__(256) void scatter_kernel(
    const int* __restrict__ src, const int* __restrict__ dst, const int* __restrict__ et,
    const int* __restrict__ cursor, const int* __restrict__ prefE,
    int* __restrict__ cur2, int4* __restrict__ eidx, int* __restrict__ relrow,
    int E, int R, int nbE) {
  __shared__ int lh[128];
  __shared__ int lbase[128];
  int t = threadIdx.x, b = blockIdx.x;
  if (t < R) {
    lh[t] = 0;
    lbase[t] = cursor[t] + prefE[t * nbE + b] - prefE[t * nbE];
  }
  __syncthreads();
  int e = b * 256 + t;
  if (e < E) {
    int r = et[e], s = src[e], d = dst[e];
    int lr = atomicAdd(&lh[r], 1);          // within-block rank (LDS)
    int jd = atomicAdd(&cur2[d], 1);        // dst-sorted msg row (distributed)
    int pos = lbase[r] + lr;
    eidx[pos] = make_int4(s, jd, r, r);
    relrow[jd] = r;
  }
}

// ---- fp32 -> bf16 convert (node features) ----
__global__ __launch_bounds__(256) void cvt_x_kernel(
    const float* __restrict__ x, unsigned short* __restrict__ xb, int n) {
  int i = blockIdx.x * 256 + threadIdx.x;
  if (i < n) xb[i] = f2bf(x[i]);
}

// ---- W[r][k][n] fp32 -> WT[r][n][k] bf16 ----
__global__ __launch_bounds__(256) void cvt_w_kernel(
    const float* __restrict__ W, unsigned short* __restrict__ WT, int total) {
  int i = blockIdx.x * 256 + threadIdx.x;
  if (i >= total) return;
  int n = i & 63, k = (i >> 6) & 63, r = i >> 12;
  WT[(r << 12) + (n << 6) + k] = f2bf(W[(r << 12) + (k << 6) + n]);
}

// ---- Phase A: MFMA matvec, stream raw msgs (packed bf16, no atomics) ----
// msg row layout (32 dwords): dword o<16 = cols (o, o+16); o>=16 = cols (o+16, o+32).
__global__ __launch_bounds__(256) __attribute__((amdgpu_waves_per_eu(1, 4)))
void msg_kernel(const unsigned short* __restrict__ xb,
                const unsigned short* __restrict__ WT,
                const int4* __restrict__ eidx,
                unsigned int* __restrict__ msgp, int nwaves) {
  const int lane = (int)threadIdx.x & 63;
  const int l15 = lane & 15;
  const int q = lane >> 4;
  const int wave = blockIdx.x * 4 + ((int)threadIdx.x >> 6);
  if (wave >= nwaves) return;
  const long base = (long)wave * SEG;
  int r = RFL(eidx[base].w);                // wave-uniform relation
  if (r < 0) r = 0;                          // all-pad tail wave
  const unsigned short* wb = WT + ((long)r << 12);
  bf16x8 Bf[4][2];
#pragma unroll
  for (int nt = 0; nt < 4; ++nt)
#pragma unroll
    for (int kh = 0; kh < 2; ++kh)
      Bf[nt][kh] = *(const bf16x8*)(wb + (nt * 16 + l15) * 64 + kh * 32 + q * 8);
#pragma unroll
  for (int t = 0; t < 4; ++t) {
    int4 rec = eidx[base + t * 16 + l15];
    const unsigned short* xr = xb + ((long)max(rec.x, 0) << 6);
    bf16x8 A0 = *(const bf16x8*)(xr + q * 8);
    bf16x8 A1 = *(const bf16x8*)(xr + 32 + q * 8);
    f32x4 acc0 = (f32x4)0.0f, acc1 = (f32x4)0.0f, acc2 = (f32x4)0.0f, acc3 = (f32x4)0.0f;
    acc0 = __builtin_amdgcn_mfma_f32_16x16x32_bf16(A0, Bf[0][0], acc0, 0, 0, 0);
    acc0 = __builtin_amdgcn_mfma_f32_16x16x32_bf16(A1, Bf[0][1], acc0, 0, 0, 0);
    acc1 = __builtin_amdgcn_mfma_f32_16x16x32_bf16(A0, Bf[1][0], acc1, 0, 0, 0);
    acc1 = __builtin_amdgcn_mfma_f32_16x16x32_bf16(A1, Bf[1][1], acc1, 0, 0, 0);
    acc2 = __builtin_amdgcn_mfma_f32_16x16x32_bf16(A0, Bf[2][0], acc2, 0, 0, 0);
    acc2 = __builtin_amdgcn_mfma_f32_16x16x32_bf16(A1, Bf[2][1], acc2, 0, 0, 0);
    acc3 = __builtin_amdgcn_mfma_f32_16x16x32_bf16(A0, Bf[3][0], acc3, 0, 0, 0);
    acc3 = __builtin_amdgcn_mfma_f32_16x16x32_bf16(A1, Bf[3][1], acc3, 0, 0, 0);
#pragma unroll
    for (int rg = 0; rg < 4; ++rg) {
      int row = q * 4 + rg;                  // C/D row = edge within tile
      int jd = __shfl(rec.y, row);           // dst-sorted msg row id (-1 = pad)
      if (jd >= 0) {
        unsigned p0 = (unsigned)f2bf(acc0[rg]) | ((unsigned)f2bf(acc1[rg]) << 16);
        unsigned p1 = (unsigned)f2bf(acc2[rg]) | ((unsigned)f2bf(acc3[rg]) << 16);
        unsigned int* mp = msgp + (long)jd * 32;
        mp[l15] = p0;
        mp[16 + l15] = p1;
      }
    }
  }
}

// ---- Phase B: wave per dst; per-(dst,rel) counts derived locally in LDS ----
__global__ __launch_bounds__(256) void agg_kernel(
    const unsigned int* __restrict__ msgp, const int* __restrict__ dstoff,
    const int* __restrict__ relrow, float* __restrict__ agg, int N) {
  __shared__ int rsh[4][256];
  __shared__ float fsh[4][256];
  const int wv = (int)threadIdx.x >> 6;
  const int lane = (int)threadIdx.x & 63;
  const int j = lane & 31;
  const int half = lane >> 5;
  const int d = blockIdx.x * 4 + wv;
  if (d >= N) return;
  const int off = dstoff[d], end = dstoff[d + 1];
  const int deg = end - off;
  float aLo = 0.f, aHi = 0.f;
  if (deg > 0 && deg <= 256) {
    const int nit = (deg + 63) >> 6;
    int cl[4];
    for (int it = 0; it < nit; ++it) {
      int l = it * 64 + lane;
      if (l < deg) rsh[wv][l] = relrow[off + l];
    }
    __threadfence_block();
    for (int it = 0; it < nit; ++it) {
      int l = it * 64 + lane;
      if (l < deg) {
        int rv = rsh[wv][l];
        int c = 0;
        for (int m = 0; m < deg; ++m) c += (rsh[wv][m] == rv) ? 1 : 0;
        cl[it] = c;
      }
    }
    for (int it = 0; it < nit; ++it) {
      int l = it * 64 + lane;
      if (l < deg) fsh[wv][l] = 1.0f / (float)cl[it];
    }
    __threadfence_block();
    float a0 = 0.f, a1 = 0.f, b0 = 0.f, b1 = 0.f;
    int i = off + half;
    for (; i + 2 < end; i += 4) {
      float w0 = fsh[wv][i - off];
      float w1 = fsh[wv][i + 2 - off];
      unsigned u0 = msgp[(long)i * 32 + j];
      unsigned u1 = msgp[(long)(i + 2) * 32 + j];
      a0 = fmaf(w0, bflo(u0), a0);
      a1 = fmaf(w0, bfhi(u0), a1);
      b0 = fmaf(w1, bflo(u1), b0);
      b1 = fmaf(w1, bfhi(u1), b1);
    }
    if (i < end) {
      float w0 = fsh[wv][i - off];
      unsigned u0 = msgp[(long)i * 32 + j];
      a0 = fmaf(w0, bflo(u0), a0);
      a1 = fmaf(w0, bfhi(u0), a1);
    }
    aLo = a0 + b0;
    aHi = a1 + b1;
  } else if (deg > 256) {
    for (int i = off + half; i < end; i += 2) {
      int rv = relrow[i];
      int c = 0;
      for (int m = off; m < end; ++m) c += (relrow[m] == rv) ? 1 : 0;
      float w = 1.0f / (float)c;
      unsigned u0 = msgp[(long)i * 32 + j];
      aLo = fmaf(w, bflo(u0), aLo);
      aHi = fmaf(w, bfhi(u0), aHi);
    }
  }
  aLo += __shfl_xor(aLo, 32);
  aHi += __shfl_xor(aHi, 32);
  if (half == 0) {
    int colLo = (j < 16) ? j : j + 16;       // cols {0..15, 32..47}
    agg[(long)d * D + colLo] = aLo;
    agg[(long)d * D + colLo + 16] = aHi;     // cols {16..31, 48..63}
  }
}

// ---- out = relu(agg + x @ Wl) (exact fp32), optionally emit bf16 copy ----
#define REP16(M) M(0) M(1) M(2) M(3) M(4) M(5) M(6) M(7) \
                 M(8) M(9) M(10) M(11) M(12) M(13) M(14) M(15)
#define W_DECL(i) float4 wq##i;
#define W_LOAD(i) wq##i = make_float4(wp[(4*i+0)*64], wp[(4*i+1)*64], \
                                      wp[(4*i+2)*64], wp[(4*i+3)*64]);
#define W_FMA(i)  { float4 xv = xr[i]; \
    acc0 = fmaf(xv.x, wq##i.x, acc0); acc1 = fmaf(xv.y, wq##i.y, acc1); \
    acc0 = fmaf(xv.z, wq##i.z, acc0); acc1 = fmaf(xv.w, wq##i.w, acc1); }

__global__ __launch_bounds__(256) __attribute__((amdgpu_waves_per_eu(1, 4)))
void selfloop_kernel(const float* __restrict__ x, const float* __restrict__ Wl,
                     const float* __restrict__ agg, float* __restrict__ out,
                     unsigned short* __restrict__ hb, int N) {
  const int lane = (int)threadIdx.x & 63;
  const int wave = blockIdx.x * 4 + ((int)threadIdx.x >> 6);
  long base = (long)wave * SL_K;
  if (base >= N) return;
  long end = base + SL_K;
  if (end > N) end = N;
  const float* wp = Wl + lane;
  REP16(W_DECL)
  REP16(W_LOAD)
  for (long n = base; n < end; ++n) {
    float acc0 = agg[n * D + lane], acc1 = 0.f;
    const float4* xr = (const float4*)(x + n * D);
    REP16(W_FMA)
    float v = fmaxf(acc0 + acc1, 0.0f);
    out[n * D + lane] = v;
    if (hb) hb[n * D + lane] = f2bf(v);
  }
}

extern "C" void kernel_launch(void* const* d_in, const int* in_sizes, int n_in,
                              void* d_out, int out_size, void* d_ws, size_t ws_size,
                              hipStream_t stream) {
  const float* x   = (const float*)d_in[0];
  const int* src   = (const int*)d_in[1];
  const int* dst   = (const int*)d_in[2];
  const int* et    = (const int*)d_in[3];
  const float* W1  = (const float*)d_in[4];
  const float* Wl1 = (const float*)d_in[5];
  const float* W2  = (const float*)d_in[6];
  const float* Wl2 = (const float*)d_in[7];
  float* out = (float*)d_out;

  const int N = in_sizes[0] / D;
  const int E = in_sizes[1];
  const int R = in_sizes[4] / (D * D);

  const int Ecap = ((E + SEG - 1) & ~(SEG - 1)) + R * SEG;
  const int nwaves = Ecap / SEG;
  const int nbN = (N + 255) / 256;          // blocks over nodes
  const int nbE = (E + 255) / 256;          // blocks over edges
  const int nBC = R * nbE;                  // bcnt length
  const int nbBC = (nBC + 255) / 256;       // scan blocks over bcnt
  const int nbMax = (nbBC > nbN) ? nbBC : nbN;

  char* ws = (char*)d_ws;
  size_t off = 0;
  auto alloc = [&](size_t bytes) -> void* {
    void* p = (void*)(ws + off);
    off += (bytes + 255) & ~(size_t)255;
    return p;
  };
  int*   cursor = (int*)alloc((size_t)R * sizeof(int));
  int*   deg    = (int*)alloc((size_t)N * sizeof(int));
  int*   bcnt   = (int*)alloc((size_t)nBC * sizeof(int));
  int*   prefE  = (int*)alloc((size_t)(nBC + 1) * sizeof(int));
  int*   bsum   = (int*)alloc((size_t)nbMax * sizeof(int));
  int*   dstoff = (int*)alloc((size_t)(N + 1) * sizeof(int));
  int*   cur2   = (int*)alloc((size_t)N * sizeof(int));
  int*   relrow = (int*)alloc((size_t)E * sizeof(int));
  int4*  eidx   = (int4*)alloc((size_t)(Ecap + SEG) * sizeof(int4));
  unsigned int* msgp = (unsigned int*)alloc((size_t)E * 32 * sizeof(unsigned int));
  float* agg    = (float*)alloc((size_t)N * D * sizeof(float));
  float* h      = (float*)alloc((size_t)N * D * sizeof(float));
  unsigned short* xb  = (unsigned short*)alloc((size_t)N * D * sizeof(unsigned short));
  unsigned short* hb  = (unsigned short*)alloc((size_t)N * D * sizeof(unsigned short));
  unsigned short* WT1 = (unsigned short*)alloc((size_t)R * D * D * sizeof(unsigned short));
  unsigned short* WT2 = (unsigned short*)alloc((size_t)R * D * D * sizeof(unsigned short));
  (void)ws_size; (void)n_in; (void)out_size;

  const int msg_blocks = (nwaves + 3) / 4;
  const int agg_blocks = (N + 3) / 4;
  const int sl_waves = (N + SL_K - 1) / SL_K;
  const int sl_blocks = (sl_waves + 3) / 4;
  const int wtot = R * D * D;

  // ---- shared preprocessing ----
  hipMemsetAsync(deg, 0, (size_t)N * sizeof(int), stream);
  hipMemsetAsync(eidx, 0xFF, (size_t)(Ecap + SEG) * sizeof(int4), stream);
  count_kernel<<<nbE, 256, 0, stream>>>(dst, et, bcnt, deg, E, R, nbE);
  // scan bcnt -> prefE (per-(rel,block) exclusive bases)
  scanA_kernel<<<nbBC, 256, 0, stream>>>(bcnt, bsum, nBC);
  scanB_kernel<<<1, 256, 0, stream>>>(bsum, nbBC);
  scanC_pref_kernel<<<nbBC, 256, 0, stream>>>(bcnt, bsum, prefE, nBC);
  prefix_kernel<<<1, 128, 0, stream>>>(prefE, cursor, nbE, R);
  // scan deg -> dstoff / cur2
  scanA_kernel<<<nbN, 256, 0, stream>>>(deg, bsum, N);
  scanB_kernel<<<1, 256, 0, stream>>>(bsum, nbN);
  scanC_deg_kernel<<<nbN, 256, 0, stream>>>(deg, bsum, dstoff, cur2, N);
  scatter_kernel<<<nbE, 256, 0, stream>>>(src, dst, et, cursor, prefE, cur2,
                                          eidx, relrow, E, R, nbE);
  cvt_x_kernel<<<(N * D + 255) / 256, 256, 0, stream>>>(x, xb, N * D);
  cvt_w_kernel<<<(wtot + 255) / 256, 256, 0, stream>>>(W1, WT1, wtot);
  cvt_w_kernel<<<(wtot + 255) / 256, 256, 0, stream>>>(W2, WT2, wtot);

  // ---- layer 1 ----
  msg_kernel<<<msg_blocks, 256, 0, stream>>>(xb, WT1, eidx, msgp, nwaves);
  agg_kernel<<<agg_blocks, 256, 0, stream>>>(msgp, dstoff, relrow, agg, N);
  selfloop_kernel<<<sl_blocks, 256, 0, stream>>>(x, Wl1, agg, h, hb, N);

  // ---- layer 2 ----
  msg_kernel<<<msg_blocks, 256, 0, stream>>>(hb, WT2, eidx, msgp, nwaves);
  agg_kernel<<<agg_blocks, 256, 0, stream>>>(msgp, dstoff, relrow, agg, N);
  selfloop_kernel<<<sl_blocks, 256, 0, stream>>>(h, Wl2, agg, out, nullptr, N);
}

// Round 9
// 371.291 us; speedup vs baseline: 1.9665x; 1.2641x over previous
//
#include <hip/hip_runtime.h>

typedef __attribute__((ext_vector_type(8))) short bf16x8;
typedef __attribute__((ext_vector_type(4))) float f32x4;

#define RFL(v) __builtin_amdgcn_readfirstlane(v)

constexpr int D = 64;
constexpr int SEG = 64;   // relation-segment padding granule = edges per wave

__device__ inline unsigned short f2bf(float f) {  // RNE fp32->bf16
  unsigned u = __float_as_uint(f);
  u += 0x7fff + ((u >> 16) & 1);
  return (unsigned short)(u >> 16);
}
__device__ inline float bflo(unsigned u) { return __uint_as_float(u << 16); }
__device__ inline float bfhi(unsigned u) { return __uint_as_float(u & 0xffff0000u); }

// ---- counting: per-block relation histogram -> bcnt[r*nbE+b]; deg atomics ----
__global__ __launch_bounds__(256) void count_kernel(
    const int* __restrict__ dst, const int* __restrict__ et,
    int* __restrict__ bcnt, int* __restrict__ deg, int E, int R, int nbE) {
  __shared__ int lh[128];
  int t = threadIdx.x;
  if (t < 128) lh[t] = 0;
  __syncthreads();
  int e = blockIdx.x * 256 + t;
  if (e < E) {
    atomicAdd(&deg[dst[e]], 1);
    atomicAdd(&lh[et[e]], 1);
  }
  __syncthreads();
  if (t < R) bcnt[t * nbE + blockIdx.x] = lh[t];  // no global hist atomics
}

// ---- generic 3-phase exclusive scan: A) block sums, B) scan sums, C) rescan ----
__global__ __launch_bounds__(256) void scanA_kernel(
    const int* __restrict__ arr, int* __restrict__ bsum, int n) {
  __shared__ int s[256];
  int t = threadIdx.x;
  int i = blockIdx.x * 256 + t;
  s[t] = (i < n) ? arr[i] : 0;
  __syncthreads();
  for (int o = 128; o > 0; o >>= 1) {
    if (t < o) s[t] += s[t + o];
    __syncthreads();
  }
  if (t == 0) bsum[blockIdx.x] = s[0];
}

__global__ __launch_bounds__(256) void scanB_kernel(int* __restrict__ bsum, int nb) {
  __shared__ int s[256];
  __shared__ int carry;
  int t = threadIdx.x;
  if (t == 0) carry = 0;
  __syncthreads();
  for (int base = 0; base < nb; base += 256) {
    int i = base + t;
    int v = (i < nb) ? bsum[i] : 0;
    s[t] = v;
    __syncthreads();
    for (int o = 1; o < 256; o <<= 1) {
      int u = (t >= o) ? s[t - o] : 0;
      __syncthreads();
      s[t] += u;
      __syncthreads();
    }
    if (i < nb) bsum[i] = carry + s[t] - v;   // exclusive
    __syncthreads();
    if (t == 0) carry += s[255];
    __syncthreads();
  }
}

// writes pref[i] (exclusive) and pref[n] = total
__global__ __launch_bounds__(256) void scanC_pref_kernel(
    const int* __restrict__ arr, const int* __restrict__ bsum,
    int* __restrict__ pref, int n) {
  __shared__ int s[256];
  int t = threadIdx.x;
  int i = blockIdx.x * 256 + t;
  int v = (i < n) ? arr[i] : 0;
  s[t] = v;
  __syncthreads();
  for (int o = 1; o < 256; o <<= 1) {
    int u = (t >= o) ? s[t - o] : 0;
    __syncthreads();
    s[t] += u;
    __syncthreads();
  }
  int excl = bsum[blockIdx.x] + s[t] - v;
  if (i < n) pref[i] = excl;
  if (i == n - 1) pref[n] = excl + v;
}

// deg variant: writes dstoff (N+1) and working copy cur2
__global__ __launch_bounds__(256) void scanC_deg_kernel(
    const int* __restrict__ deg, const int* __restrict__ bsum,
    int* __restrict__ dstoff, int* __restrict__ cur2, int N) {
  __shared__ int s[256];
  int t = threadIdx.x;
  int i = blockIdx.x * 256 + t;
  int v = (i < N) ? deg[i] : 0;
  s[t] = v;
  __syncthreads();
  for (int o = 1; o < 256; o <<= 1) {
    int u = (t >= o) ? s[t - o] : 0;
    __syncthreads();
    s[t] += u;
    __syncthreads();
  }
  int excl = bsum[blockIdx.x] + s[t] - v;
  if (i < N) { dstoff[i] = excl; cur2[i] = excl; }
  if (i == N - 1) dstoff[N] = excl + v;
}

// ---- padded relation cursors from bcnt-scan boundary values ----
__global__ void prefix_kernel(const int* __restrict__ prefE,
                              int* __restrict__ cursor, int nbE, int R) {
  __shared__ int sc[128];
  int l = threadIdx.x;
  int c = 0;
  if (l < R) {
    int tot = prefE[(l + 1) * nbE] - prefE[l * nbE];
    c = (tot + SEG - 1) & ~(SEG - 1);
  }
  sc[l] = c;
  __syncthreads();
  for (int ofs = 1; ofs < 128; ofs <<= 1) {
    int v = (l >= ofs) ? sc[l - ofs] : 0;
    __syncthreads();
    sc[l] += v;
    __syncthreads();
  }
  if (l < R) cursor[l] = sc[l] - c;
}

// ---- counting-sort scatter: block bases precomputed (no cursor atomics) ----
// eidx[pos]={src,jd,rel,rel}; relrow[jd]=rel. Pads stay 0xFF (jd=-1).
__global__ __launch_bounds__(256) void scatter_kernel(
    const int* __restrict__ src, const int* __restrict__ dst, const int* __restrict__ et,
    const int* __restrict__ cursor, const int* __restrict__ prefE,
    int* __restrict__ cur2, int4* __restrict__ eidx, int* __restrict__ relrow,
    int E, int R, int nbE) {
  __shared__ int lh[128];
  __shared__ int lbase[128];
  int t = threadIdx.x, b = blockIdx.x;
  if (t < R) {
    lh[t] = 0;
    lbase[t] = cursor[t] + prefE[t * nbE + b] - prefE[t * nbE];
  }
  __syncthreads();
  int e = b * 256 + t;
  if (e < E) {
    int r = et[e], s = src[e], d = dst[e];
    int lr = atomicAdd(&lh[r], 1);          // within-block rank (LDS)
    int jd = atomicAdd(&cur2[d], 1);        // dst-sorted msg row (distributed)
    int pos = lbase[r] + lr;
    eidx[pos] = make_int4(s, jd, r, r);
    relrow[jd] = r;
  }
}

// ---- fp32 -> bf16 convert (node features) ----
__global__ __launch_bounds__(256) void cvt_x_kernel(
    const float* __restrict__ x, unsigned short* __restrict__ xb, int n) {
  int i = blockIdx.x * 256 + threadIdx.x;
  if (i < n) xb[i] = f2bf(x[i]);
}

// ---- W[k][n] fp32 -> WT[n][k] bf16 (per 64x64 block; works for W[R] and Wl) ----
__global__ __launch_bounds__(256) void cvt_w_kernel(
    const float* __restrict__ W, unsigned short* __restrict__ WT, int total) {
  int i = blockIdx.x * 256 + threadIdx.x;
  if (i >= total) return;
  int n = i & 63, k = (i >> 6) & 63, r = i >> 12;
  WT[(r << 12) + (n << 6) + k] = f2bf(W[(r << 12) + (k << 6) + n]);
}

// ---- Phase A: MFMA matvec, stream raw msgs (packed bf16, no atomics) ----
// msg row layout (32 dwords): dword o<16 = cols (o, o+16); o>=16 = cols (o+16, o+32).
__global__ __launch_bounds__(256) __attribute__((amdgpu_waves_per_eu(1, 4)))
void msg_kernel(const unsigned short* __restrict__ xb,
                const unsigned short* __restrict__ WT,
                const int4* __restrict__ eidx,
                unsigned int* __restrict__ msgp, int nwaves) {
  const int lane = (int)threadIdx.x & 63;
  const int l15 = lane & 15;
  const int q = lane >> 4;
  const int wave = blockIdx.x * 4 + ((int)threadIdx.x >> 6);
  if (wave >= nwaves) return;
  const long base = (long)wave * SEG;
  int r = RFL(eidx[base].w);                // wave-uniform relation
  if (r < 0) r = 0;                          // all-pad tail wave
  const unsigned short* wb = WT + ((long)r << 12);
  bf16x8 Bf[4][2];
#pragma unroll
  for (int nt = 0; nt < 4; ++nt)
#pragma unroll
    for (int kh = 0; kh < 2; ++kh)
      Bf[nt][kh] = *(const bf16x8*)(wb + (nt * 16 + l15) * 64 + kh * 32 + q * 8);
#pragma unroll
  for (int t = 0; t < 4; ++t) {
    int4 rec = eidx[base + t * 16 + l15];
    const unsigned short* xr = xb + ((long)max(rec.x, 0) << 6);
    bf16x8 A0 = *(const bf16x8*)(xr + q * 8);
    bf16x8 A1 = *(const bf16x8*)(xr + 32 + q * 8);
    f32x4 acc0 = (f32x4)0.0f, acc1 = (f32x4)0.0f, acc2 = (f32x4)0.0f, acc3 = (f32x4)0.0f;
    acc0 = __builtin_amdgcn_mfma_f32_16x16x32_bf16(A0, Bf[0][0], acc0, 0, 0, 0);
    acc0 = __builtin_amdgcn_mfma_f32_16x16x32_bf16(A1, Bf[0][1], acc0, 0, 0, 0);
    acc1 = __builtin_amdgcn_mfma_f32_16x16x32_bf16(A0, Bf[1][0], acc1, 0, 0, 0);
    acc1 = __builtin_amdgcn_mfma_f32_16x16x32_bf16(A1, Bf[1][1], acc1, 0, 0, 0);
    acc2 = __builtin_amdgcn_mfma_f32_16x16x32_bf16(A0, Bf[2][0], acc2, 0, 0, 0);
    acc2 = __builtin_amdgcn_mfma_f32_16x16x32_bf16(A1, Bf[2][1], acc2, 0, 0, 0);
    acc3 = __builtin_amdgcn_mfma_f32_16x16x32_bf16(A0, Bf[3][0], acc3, 0, 0, 0);
    acc3 = __builtin_amdgcn_mfma_f32_16x16x32_bf16(A1, Bf[3][1], acc3, 0, 0, 0);
#pragma unroll
    for (int rg = 0; rg < 4; ++rg) {
      int row = q * 4 + rg;                  // C/D row = edge within tile
      int jd = __shfl(rec.y, row);           // dst-sorted msg row id (-1 = pad)
      if (jd >= 0) {
        unsigned p0 = (unsigned)f2bf(acc0[rg]) | ((unsigned)f2bf(acc1[rg]) << 16);
        unsigned p1 = (unsigned)f2bf(acc2[rg]) | ((unsigned)f2bf(acc3[rg]) << 16);
        unsigned int* mp = msgp + (long)jd * 32;
        mp[l15] = p0;
        mp[16 + l15] = p1;
      }
    }
  }
}

// ---- Phase B: wave per dst; per-(dst,rel) counts derived locally in LDS ----
__global__ __launch_bounds__(256) void agg_kernel(
    const unsigned int* __restrict__ msgp, const int* __restrict__ dstoff,
    const int* __restrict__ relrow, float* __restrict__ agg, int N) {
  __shared__ int rsh[4][256];
  __shared__ float fsh[4][256];
  const int wv = (int)threadIdx.x >> 6;
  const int lane = (int)threadIdx.x & 63;
  const int j = lane & 31;
  const int half = lane >> 5;
  const int d = blockIdx.x * 4 + wv;
  if (d >= N) return;
  const int off = dstoff[d], end = dstoff[d + 1];
  const int deg = end - off;
  float aLo = 0.f, aHi = 0.f;
  if (deg > 0 && deg <= 256) {
    const int nit = (deg + 63) >> 6;
    int cl[4];
    for (int it = 0; it < nit; ++it) {
      int l = it * 64 + lane;
      if (l < deg) rsh[wv][l] = relrow[off + l];
    }
    __threadfence_block();
    for (int it = 0; it < nit; ++it) {
      int l = it * 64 + lane;
      if (l < deg) {
        int rv = rsh[wv][l];
        int c = 0;
        for (int m = 0; m < deg; ++m) c += (rsh[wv][m] == rv) ? 1 : 0;
        cl[it] = c;
      }
    }
    for (int it = 0; it < nit; ++it) {
      int l = it * 64 + lane;
      if (l < deg) fsh[wv][l] = 1.0f / (float)cl[it];
    }
    __threadfence_block();
    float a0 = 0.f, a1 = 0.f, b0 = 0.f, b1 = 0.f;
    int i = off + half;
    for (; i + 2 < end; i += 4) {
      float w0 = fsh[wv][i - off];
      float w1 = fsh[wv][i + 2 - off];
      unsigned u0 = msgp[(long)i * 32 + j];
      unsigned u1 = msgp[(long)(i + 2) * 32 + j];
      a0 = fmaf(w0, bflo(u0), a0);
      a1 = fmaf(w0, bfhi(u0), a1);
      b0 = fmaf(w1, bflo(u1), b0);
      b1 = fmaf(w1, bfhi(u1), b1);
    }
    if (i < end) {
      float w0 = fsh[wv][i - off];
      unsigned u0 = msgp[(long)i * 32 + j];
      a0 = fmaf(w0, bflo(u0), a0);
      a1 = fmaf(w0, bfhi(u0), a1);
    }
    aLo = a0 + b0;
    aHi = a1 + b1;
  } else if (deg > 256) {
    for (int i = off + half; i < end; i += 2) {
      int rv = relrow[i];
      int c = 0;
      for (int m = off; m < end; ++m) c += (relrow[m] == rv) ? 1 : 0;
      float w = 1.0f / (float)c;
      unsigned u0 = msgp[(long)i * 32 + j];
      aLo = fmaf(w, bflo(u0), aLo);
      aHi = fmaf(w, bfhi(u0), aHi);
    }
  }
  aLo += __shfl_xor(aLo, 32);
  aHi += __shfl_xor(aHi, 32);
  if (half == 0) {
    int colLo = (j < 16) ? j : j + 16;       // cols {0..15, 32..47}
    agg[(long)d * D + colLo] = aLo;
    agg[(long)d * D + colLo + 16] = aHi;     // cols {16..31, 48..63}
  }
}

// ---- self-loop as MFMA GEMM: out = relu(agg + xb @ Wl), agg as C-operand ----
// One wave per 64 nodes. A = xb rows (per-lane coalesced), B = WTl frags.
__global__ __launch_bounds__(256) void selfloop_kernel(
    const unsigned short* __restrict__ xbin, const unsigned short* __restrict__ WTl,
    const float* __restrict__ agg, float* __restrict__ out,
    unsigned short* __restrict__ hb, int N) {
  const int lane = (int)threadIdx.x & 63;
  const int l15 = lane & 15;
  const int q = lane >> 4;
  const int wave = blockIdx.x * 4 + ((int)threadIdx.x >> 6);
  const int base = wave * 64;
  if (base >= N) return;
  bf16x8 Bf[4][2];
#pragma unroll
  for (int nt = 0; nt < 4; ++nt)
#pragma unroll
    for (int kh = 0; kh < 2; ++kh)
      Bf[nt][kh] = *(const bf16x8*)(WTl + (nt * 16 + l15) * 64 + kh * 32 + q * 8);
#pragma unroll
  for (int t = 0; t < 4; ++t) {
    const int row0 = base + t * 16;
    if (row0 >= N) break;
    const int m = min(row0 + l15, N - 1);
    const unsigned short* xr = xbin + ((long)m << 6);
    bf16x8 A0 = *(const bf16x8*)(xr + q * 8);
    bf16x8 A1 = *(const bf16x8*)(xr + 32 + q * 8);
    f32x4 acc[4];
#pragma unroll
    for (int nt = 0; nt < 4; ++nt) {
#pragma unroll
      for (int rg = 0; rg < 4; ++rg) {
        int node = row0 + q * 4 + rg;
        acc[nt][rg] = (node < N) ? agg[(long)node * D + nt * 16 + l15] : 0.0f;
      }
    }
#pragma unroll
    for (int nt = 0; nt < 4; ++nt) {
      acc[nt] = __builtin_amdgcn_mfma_f32_16x16x32_bf16(A0, Bf[nt][0], acc[nt], 0, 0, 0);
      acc[nt] = __builtin_amdgcn_mfma_f32_16x16x32_bf16(A1, Bf[nt][1], acc[nt], 0, 0, 0);
    }
#pragma unroll
    for (int rg = 0; rg < 4; ++rg) {
      int node = row0 + q * 4 + rg;
      if (node < N) {
#pragma unroll
        for (int nt = 0; nt < 4; ++nt) {
          float v = fmaxf(acc[nt][rg], 0.0f);
          out[(long)node * D + nt * 16 + l15] = v;
          if (hb) hb[(long)node * D + nt * 16 + l15] = f2bf(v);
        }
      }
    }
  }
}

extern "C" void kernel_launch(void* const* d_in, const int* in_sizes, int n_in,
                              void* d_out, int out_size, void* d_ws, size_t ws_size,
                              hipStream_t stream) {
  const float* x   = (const float*)d_in[0];
  const int* src   = (const int*)d_in[1];
  const int* dst   = (const int*)d_in[2];
  const int* et    = (const int*)d_in[3];
  const float* W1  = (const float*)d_in[4];
  const float* Wl1 = (const float*)d_in[5];
  const float* W2  = (const float*)d_in[6];
  const float* Wl2 = (const float*)d_in[7];
  float* out = (float*)d_out;

  const int N = in_sizes[0] / D;
  const int E = in_sizes[1];
  const int R = in_sizes[4] / (D * D);

  const int Ecap = ((E + SEG - 1) & ~(SEG - 1)) + R * SEG;
  const int nwaves = Ecap / SEG;
  const int nbN = (N + 255) / 256;          // blocks over nodes
  const int nbE = (E + 255) / 256;          // blocks over edges
  const int nBC = R * nbE;                  // bcnt length
  const int nbBC = (nBC + 255) / 256;       // scan blocks over bcnt
  const int nbMax = (nbBC > nbN) ? nbBC : nbN;

  char* ws = (char*)d_ws;
  size_t off = 0;
  auto alloc = [&](size_t bytes) -> void* {
    void* p = (void*)(ws + off);
    off += (bytes + 255) & ~(size_t)255;
    return p;
  };
  int*   cursor = (int*)alloc((size_t)R * sizeof(int));
  int*   deg    = (int*)alloc((size_t)N * sizeof(int));
  int*   bcnt   = (int*)alloc((size_t)nBC * sizeof(int));
  int*   prefE  = (int*)alloc((size_t)(nBC + 1) * sizeof(int));
  int*   bsum   = (int*)alloc((size_t)nbMax * sizeof(int));
  int*   dstoff = (int*)alloc((size_t)(N + 1) * sizeof(int));
  int*   cur2   = (int*)alloc((size_t)N * sizeof(int));
  int*   relrow = (int*)alloc((size_t)E * sizeof(int));
  int4*  eidx   = (int4*)alloc((size_t)(Ecap + SEG) * sizeof(int4));
  unsigned int* msgp = (unsigned int*)alloc((size_t)E * 32 * sizeof(unsigned int));
  float* agg    = (float*)alloc((size_t)N * D * sizeof(float));
  unsigned short* xb  = (unsigned short*)alloc((size_t)N * D * sizeof(unsigned short));
  unsigned short* hb  = (unsigned short*)alloc((size_t)N * D * sizeof(unsigned short));
  unsigned short* WT1 = (unsigned short*)alloc((size_t)R * D * D * sizeof(unsigned short));
  unsigned short* WT2 = (unsigned short*)alloc((size_t)R * D * D * sizeof(unsigned short));
  unsigned short* WTl1 = (unsigned short*)alloc((size_t)D * D * sizeof(unsigned short));
  unsigned short* WTl2 = (unsigned short*)alloc((size_t)D * D * sizeof(unsigned short));
  (void)ws_size; (void)n_in; (void)out_size;

  const int msg_blocks = (nwaves + 3) / 4;
  const int agg_blocks = (N + 3) / 4;
  const int sl_waves = (N + 63) / 64;
  const int sl_blocks = (sl_waves + 3) / 4;
  const int wtot = R * D * D;

  // ---- shared preprocessing ----
  hipMemsetAsync(deg, 0, (size_t)N * sizeof(int), stream);
  hipMemsetAsync(eidx, 0xFF, (size_t)(Ecap + SEG) * sizeof(int4), stream);
  count_kernel<<<nbE, 256, 0, stream>>>(dst, et, bcnt, deg, E, R, nbE);
  // scan bcnt -> prefE (per-(rel,block) exclusive bases)
  scanA_kernel<<<nbBC, 256, 0, stream>>>(bcnt, bsum, nBC);
  scanB_kernel<<<1, 256, 0, stream>>>(bsum, nbBC);
  scanC_pref_kernel<<<nbBC, 256, 0, stream>>>(bcnt, bsum, prefE, nBC);
  prefix_kernel<<<1, 128, 0, stream>>>(prefE, cursor, nbE, R);
  // scan deg -> dstoff / cur2
  scanA_kernel<<<nbN, 256, 0, stream>>>(deg, bsum, N);
  scanB_kernel<<<1, 256, 0, stream>>>(bsum, nbN);
  scanC_deg_kernel<<<nbN, 256, 0, stream>>>(deg, bsum, dstoff, cur2, N);
  scatter_kernel<<<nbE, 256, 0, stream>>>(src, dst, et, cursor, prefE, cur2,
                                          eidx, relrow, E, R, nbE);
  cvt_x_kernel<<<(N * D + 255) / 256, 256, 0, stream>>>(x, xb, N * D);
  cvt_w_kernel<<<(wtot + 255) / 256, 256, 0, stream>>>(W1, WT1, wtot);
  cvt_w_kernel<<<(wtot + 255) / 256, 256, 0, stream>>>(W2, WT2, wtot);
  cvt_w_kernel<<<(D * D + 255) / 256, 256, 0, stream>>>(Wl1, WTl1, D * D);
  cvt_w_kernel<<<(D * D + 255) / 256, 256, 0, stream>>>(Wl2, WTl2, D * D);

  // ---- layer 1 ----
  msg_kernel<<<msg_blocks, 256, 0, stream>>>(xb, WT1, eidx, msgp, nwaves);
  agg_kernel<<<agg_blocks, 256, 0, stream>>>(msgp, dstoff, relrow, agg, N);
  selfloop_kernel<<<sl_blocks, 256, 0, stream>>>(xb, WTl1, agg, out, hb, N);

  // ---- layer 2 ----
  msg_kernel<<<msg_blocks, 256, 0, stream>>>(hb, WT2, eidx, msgp, nwaves);
  agg_kernel<<<agg_blocks, 256, 0, stream>>>(msgp, dstoff, relrow, agg, N);
  selfloop_kernel<<<sl_blocks, 256, 0, stream>>>(hb, WTl2, agg, out, nullptr, N);
}